// Round 11
// baseline (635.351 us; speedup 1.0000x reference)
//
#include <hip/hip_runtime.h>
#include <math.h>

#define SELU_ALPHA 1.6732632423543772f
#define SELU_SCALE 1.0507009873554805f

#define NBLK 512          // partition blocks (E divides exactly: 512*3125)
#define MAXBKT 512        // static LDS sizing; actual NBKT = ceil(N/256)

typedef __attribute__((ext_vector_type(8))) short bf16x8;
typedef __attribute__((ext_vector_type(4))) float f32x4;

__device__ __forceinline__ float selu_f(float x) {
    return SELU_SCALE * (x > 0.f ? x : SELU_ALPHA * expm1f(x));
}

__device__ __forceinline__ float bf2f(unsigned short u) {
    return __uint_as_float(((unsigned)u) << 16);
}
__device__ __forceinline__ unsigned short f2bf(float f) {
    unsigned u = __float_as_uint(f);
    unsigned r = (u + 0x7fffu + ((u >> 16) & 1u)) >> 16;
    return (unsigned short)r;
}

// ---- exclusive scan (3 kernels), in-place safe; used on concatenated cntD|cntS ----
#define SCAN_B 1024

__global__ __launch_bounds__(256) void scan_block_sums(const int* __restrict__ in,
                                                       int* __restrict__ bsums, int n) {
    __shared__ int s[256];
    int b = blockIdx.x, t = threadIdx.x;
    int base = b * SCAN_B;
    int sum = 0;
    for (int i = t; i < SCAN_B; i += 256) {
        int idx = base + i;
        sum += (idx < n) ? in[idx] : 0;
    }
    s[t] = sum; __syncthreads();
    for (int off = 128; off > 0; off >>= 1) {
        if (t < off) s[t] += s[t + off];
        __syncthreads();
    }
    if (t == 0) bsums[b] = s[0];
}

__global__ __launch_bounds__(256) void scan_bsums(int* __restrict__ bsums, int nb) {
    __shared__ int s[256];
    __shared__ int carry_s;
    int t = threadIdx.x;
    if (t == 0) carry_s = 0;
    __syncthreads();
    for (int base = 0; base < nb; base += 256) {
        int idx = base + t;
        int v = (idx < nb) ? bsums[idx] : 0;
        s[t] = v; __syncthreads();
        for (int off = 1; off < 256; off <<= 1) {
            int x = (t >= off) ? s[t - off] : 0;
            __syncthreads();
            s[t] += x;
            __syncthreads();
        }
        int incl = s[t];
        int excl = incl - v;
        int c = carry_s;
        __syncthreads();
        if (idx < nb) bsums[idx] = c + excl;
        if (t == 255) carry_s = c + incl;
        __syncthreads();
    }
}

__global__ __launch_bounds__(256) void scan_apply(const int* __restrict__ in,
                                                  const int* __restrict__ boffs,
                                                  int* __restrict__ out, int n) {
    __shared__ int s[256];
    int b = blockIdx.x, t = threadIdx.x;
    int idx0 = b * SCAN_B + t * 4;
    int v[4]; int tsum = 0;
    #pragma unroll
    for (int k = 0; k < 4; ++k) {
        int idx = idx0 + k;
        v[k] = (idx < n) ? in[idx] : 0;
        tsum += v[k];
    }
    s[t] = tsum; __syncthreads();
    for (int off = 1; off < 256; off <<= 1) {
        int x = (t >= off) ? s[t - off] : 0;
        __syncthreads();
        s[t] += x;
        __syncthreads();
    }
    int run = s[t] - tsum + boffs[b];
    #pragma unroll
    for (int k = 0; k < 4; ++k) {
        int idx = idx0 + k;
        if (idx < n) out[idx] = run;
        run += v[k];
    }
}

// ---- K1: per-block coarse histograms of dst>>8 and src>>8 (LDS atomics only) ----
__global__ __launch_bounds__(256) void coarse_hist_kernel(
        const int* __restrict__ src, const int* __restrict__ dst,
        int* __restrict__ cntD, int* __restrict__ cntS, int E, int nbkt) {
    __shared__ int hD[MAXBKT];
    __shared__ int hS[MAXBKT];
    int bb = blockIdx.x, t = threadIdx.x;
    for (int k = t; k < MAXBKT; k += 256) { hD[k] = 0; hS[k] = 0; }
    __syncthreads();
    int chunk = E / NBLK;                 // exact
    int beg = bb * chunk, end = beg + chunk;
    for (int i = beg + t; i < end; i += 256) {
        atomicAdd(&hD[((unsigned)dst[i]) >> 8], 1);
        atomicAdd(&hS[((unsigned)src[i]) >> 8], 1);
    }
    __syncthreads();
    for (int k = t; k < nbkt; k += 256) {
        cntD[k * NBLK + bb] = hD[k];
        cntS[k * NBLK + bb] = hS[k];
    }
}

// ---- K2: scatter. cntS entries carry +E offset (concatenated scan); caller passes
//      sbufm = sbuf - E so writes land correctly. ----
__global__ __launch_bounds__(256) void scatter_kernel(
        const int* __restrict__ src, const int* __restrict__ dst,
        const int* __restrict__ cntD, const int* __restrict__ cntS,
        uint2* __restrict__ pairs, int* __restrict__ sbufm, int E, int nbkt) {
    __shared__ int cD[MAXBKT];
    __shared__ int cS[MAXBKT];
    int bb = blockIdx.x, t = threadIdx.x;
    for (int k = t; k < nbkt; k += 256) {
        cD[k] = cntD[k * NBLK + bb];
        cS[k] = cntS[k * NBLK + bb];
    }
    __syncthreads();
    int chunk = E / NBLK;
    int beg = bb * chunk, end = beg + chunk;
    for (int i = beg + t; i < end; i += 256) {
        unsigned s = (unsigned)src[i], d = (unsigned)dst[i];
        int pD = atomicAdd(&cD[d >> 8], 1);
        pairs[pD] = make_uint2(s, d);
        int pS = atomicAdd(&cS[s >> 8], 1);
        sbufm[pS] = (int)s;
    }
}

// ---- K3: fused bucket build: deg_out histogram + CSR (row_start, deg_in, csr_src) ----
__global__ __launch_bounds__(256) void bucket_build_kernel(
        const int* __restrict__ sbufm, const uint2* __restrict__ pairs,
        const int* __restrict__ cntD, const int* __restrict__ cntS,
        int* __restrict__ deg_out, int* __restrict__ row_start,
        int* __restrict__ deg_in, int* __restrict__ csr_src,
        int N, int E, int nbkt) {
    __shared__ int hist[256];
    __shared__ int sc[256];
    __shared__ int cur[256];
    int b = blockIdx.x, t = threadIdx.x;
    int node = (b << 8) + t;

    // part 1: deg_out from src-bucket values (indices carry +E offset)
    {
        int base = cntS[b * NBLK];
        int end = (b + 1 < nbkt) ? cntS[(b + 1) * NBLK] : 2 * E;
        hist[t] = 0; __syncthreads();
        for (int i = base + t; i < end; i += 256)
            atomicAdd(&hist[sbufm[i] & 255], 1);
        __syncthreads();
        if (node < N) deg_out[node] = hist[t];
        __syncthreads();
    }

    // part 2: CSR build from dst-bucket pairs
    {
        int base = cntD[b * NBLK];
        int end = (b + 1 < nbkt) ? cntD[(b + 1) * NBLK] : E;
        hist[t] = 0; __syncthreads();
        for (int i = base + t; i < end; i += 256)
            atomicAdd(&hist[pairs[i].y & 255], 1);
        __syncthreads();
        int v = hist[t];
        sc[t] = v; __syncthreads();
        for (int off = 1; off < 256; off <<= 1) {
            int x = (t >= off) ? sc[t - off] : 0;
            __syncthreads();
            sc[t] += x;
            __syncthreads();
        }
        int ex = sc[t] - v;
        cur[t] = base + ex;
        if (node < N) { row_start[node] = base + ex; deg_in[node] = v; }
        __syncthreads();
        for (int i = base + t; i < end; i += 256) {
            uint2 p = pairs[i];
            int pos = atomicAdd(&cur[p.y & 255], 1);
            csr_src[pos] = (int)p.x;
        }
    }
}

// ---- prep: all weight conversions in ONE dispatch ----
__global__ void prep_weights_kernel(
        const float* __restrict__ W1, const float* __restrict__ W2,
        const float* __restrict__ W3, const float* __restrict__ L1w,
        const float* __restrict__ L2w,
        unsigned short* __restrict__ Wt1, unsigned short* __restrict__ Wt2,
        unsigned short* __restrict__ Wt3, unsigned short* __restrict__ L1w16,
        unsigned short* __restrict__ L2w16) {
    const int s0 = 128 * 64, s1 = 128 * 128, s2 = 128 * 128;
    const int s3 = 131 * 256 / 4, s4 = 256 * 128 / 4;
    int i = blockIdx.x * 256 + threadIdx.x;
    if (i < s0) {
        int col = i / 64, k = i % 64;
        Wt1[i] = f2bf(W1[k * 128 + col]);
        return;
    }
    i -= s0;
    if (i < s1) {
        int col = i / 128, k = i % 128;
        Wt2[i] = f2bf(W2[k * 128 + col]);
        return;
    }
    i -= s1;
    if (i < s2) {
        int col = i / 128, k = i % 128;
        Wt3[i] = f2bf(W3[k * 128 + col]);
        return;
    }
    i -= s2;
    if (i < s3) {
        float4 v = reinterpret_cast<const float4*>(L1w)[i];
        unsigned short o[4] = { f2bf(v.x), f2bf(v.y), f2bf(v.z), f2bf(v.w) };
        reinterpret_cast<uint2*>(L1w16)[i] = *reinterpret_cast<uint2*>(o);
        return;
    }
    i -= s3;
    if (i < s4) {
        float4 v = reinterpret_cast<const float4*>(L2w)[i];
        unsigned short o[4] = { f2bf(v.x), f2bf(v.y), f2bf(v.z), f2bf(v.w) };
        reinterpret_cast<uint2*>(L2w16)[i] = *reinterpret_cast<uint2*>(o);
    }
}

// ---- prep: feats -> bf16 prescaled by norm_out (computed inline); stores norm_out ----
__global__ void cvt_feats_kernel(const float* __restrict__ feats,
                                 const int* __restrict__ deg_out,
                                 float* __restrict__ norm_out,
                                 unsigned short* __restrict__ outp, int N) {
    int i = blockIdx.x * blockDim.x + threadIdx.x;   // i = n*8 + chunk
    if (i >= 8 * N) return;
    int n = i >> 3, c = i & 7;
    float no = 1.f / sqrtf(fmaxf((float)deg_out[n], 1.f));
    if (c == 0) norm_out[n] = no;
    const float* fp = feats + (size_t)n * 64 + c * 8;
    float4 a = *reinterpret_cast<const float4*>(fp);
    float4 b = *reinterpret_cast<const float4*>(fp + 4);
    unsigned short o[8] = { f2bf(a.x * no), f2bf(a.y * no), f2bf(a.z * no), f2bf(a.w * no),
                            f2bf(b.x * no), f2bf(b.y * no), f2bf(b.z * no), f2bf(b.w * no) };
    *reinterpret_cast<float4*>(outp + (size_t)n * 64 + c * 8) = *reinterpret_cast<float4*>(o);
}

// ---- FUSED layer: gather-aggregate -> LDS A-tile -> MFMA GEMM -> activation -> out ----
// Tile = 128 nodes x 128 outs, 256 thr (4 waves). Agg: TPG=FIN/8 lanes/node with
// shuffle-broadcast index ILP; norm_in computed inline from deg_in.
// NOTE: x (gather input) and out MUST be distinct buffers — blocks run concurrently.
template<int FIN, bool SELU, bool SCALE_OUT>
__global__ __launch_bounds__(256, 2) void fused_layer_kernel(
        const unsigned short* __restrict__ x,      // [N][FIN] bf16, prescaled by norm_out
        const int* __restrict__ row_start, const int* __restrict__ deg_in,
        const int* __restrict__ csr_src,
        const unsigned short* __restrict__ Wt,     // [128][FIN] bf16
        const float* __restrict__ bias,
        const float* __restrict__ norm_out,
        unsigned short* __restrict__ out,          // [N][128] bf16 (!= x)
        int N) {
    const int PAD = 8;
    const int LDA = FIN + PAD;
    const int CH = FIN / 8;
    __shared__ unsigned short sA[128 * LDA];
    __shared__ unsigned short sW[128 * LDA];
    const int tid = threadIdx.x;
    const int n0 = blockIdx.x * 128;

    // stage W (coalesced 16B)
    for (int i = tid; i < 128 * CH; i += 256) {
        int col = i / CH, kc = i % CH;
        *reinterpret_cast<float4*>(&sW[col * LDA + kc * 8]) =
            *reinterpret_cast<const float4*>(&Wt[col * FIN + kc * 8]);
    }

    // aggregate phase: GPB nodes at a time
    const int TPG = FIN / 8;
    const int GPB = 256 / TPG;
    const int g = tid / TPG;
    const int j = tid % TPG;
    const int lane = tid & 63;
    const int gbase = lane & ~(TPG - 1);
    for (int base = 0; base < 128; base += GPB) {
        int row = base + g;
        int n = n0 + row;
        float acc[8] = {0.f, 0.f, 0.f, 0.f, 0.f, 0.f, 0.f, 0.f};
        float nin = 0.f;
        if (n < N) {
            int beg = row_start[n];
            int dg = deg_in[n];
            int end = beg + dg;
            nin = 1.f / sqrtf(fmaxf((float)dg, 1.f));
            for (int c = beg; c < end; c += TPG) {
                int myIdx = (c + j < end) ? csr_src[c + j] : 0;
                int cnt = end - c;             // uniform within group
                float4 v[TPG];
                #pragma unroll
                for (int t = 0; t < TPG; ++t) {
                    if (t < cnt) {
                        int s = __shfl(myIdx, gbase + t, 64);
                        v[t] = *reinterpret_cast<const float4*>(&x[(size_t)s * FIN + j * 8]);
                    }
                }
                #pragma unroll
                for (int t = 0; t < TPG; ++t) {
                    if (t < cnt) {
                        const unsigned short* u = reinterpret_cast<const unsigned short*>(&v[t]);
                        #pragma unroll
                        for (int k = 0; k < 8; ++k) acc[k] += bf2f(u[k]);
                    }
                }
            }
        }
        unsigned short ov[8];
        #pragma unroll
        for (int k = 0; k < 8; ++k) ov[k] = f2bf(acc[k] * nin);
        *reinterpret_cast<float4*>(&sA[row * LDA + j * 8]) = *reinterpret_cast<float4*>(ov);
    }
    __syncthreads();

    // MFMA phase
    const int wave = tid >> 6;
    const int wr = (wave >> 1) * 64;
    const int wc = (wave & 1) * 64;
    const int l16 = lane & 15;
    const int lk = (lane >> 4) * 8;
    f32x4 acc[4][4];
    #pragma unroll
    for (int mi = 0; mi < 4; ++mi)
        #pragma unroll
        for (int ci = 0; ci < 4; ++ci)
            acc[mi][ci] = (f32x4){0.f, 0.f, 0.f, 0.f};

    #pragma unroll
    for (int k0 = 0; k0 < FIN; k0 += 32) {
        bf16x8 a[4], w[4];
        #pragma unroll
        for (int mi = 0; mi < 4; ++mi)
            a[mi] = *reinterpret_cast<const bf16x8*>(&sA[(wr + mi * 16 + l16) * LDA + k0 + lk]);
        #pragma unroll
        for (int ci = 0; ci < 4; ++ci)
            w[ci] = *reinterpret_cast<const bf16x8*>(&sW[(wc + ci * 16 + l16) * LDA + k0 + lk]);
        #pragma unroll
        for (int mi = 0; mi < 4; ++mi)
            #pragma unroll
            for (int ci = 0; ci < 4; ++ci)
                acc[mi][ci] = __builtin_amdgcn_mfma_f32_16x16x32_bf16(
                    a[mi], w[ci], acc[mi][ci], 0, 0, 0);
    }

    // epilogue: D frag col = lane&15, row = (lane>>4)*4 + r
    const int rbase = (lane >> 4) * 4;
    #pragma unroll
    for (int ci = 0; ci < 4; ++ci) {
        int col = wc + ci * 16 + l16;
        float bv = bias[col];
        #pragma unroll
        for (int mi = 0; mi < 4; ++mi) {
            #pragma unroll
            for (int r = 0; r < 4; ++r) {
                int n = n0 + wr + mi * 16 + rbase + r;
                if (n < N) {
                    float v = acc[mi][ci][r] + bv;
                    if (SELU) v = selu_f(v);
                    if (SCALE_OUT) v *= norm_out[n];
                    out[(size_t)n * 128 + col] = f2bf(v);
                }
            }
        }
    }
}

// ---- readout with inline binary search (node2graph sorted) ----
__global__ __launch_bounds__(128) void readout_kernel(
        const unsigned short* __restrict__ y, const int* __restrict__ n2g,
        float* __restrict__ gsum, int N, int G) {
    int g = blockIdx.x;
    int o = threadIdx.x;
    if (g >= G) return;
    int beg, end;
    {
        int lo = 0, hi = N;
        while (lo < hi) { int m = (lo + hi) >> 1; if (n2g[m] < g) lo = m + 1; else hi = m; }
        beg = lo;
        lo = beg; hi = N;
        while (lo < hi) { int m = (lo + hi) >> 1; if (n2g[m] < g + 1) lo = m + 1; else hi = m; }
        end = lo;
    }
    float acc = 0.f;
    for (int n = beg; n < end; ++n)
        acc += bf2f(y[(size_t)n * 128 + o]);
    gsum[(size_t)g * 128 + o] = acc;
}

// ---- MLP head: 16 graphs per block, bf16 W staged in LDS, fp32 accumulate ----
__global__ __launch_bounds__(256) void mlp1_kernel(
        const float* __restrict__ gsum, const float* __restrict__ fg,
        const unsigned short* __restrict__ W16,    // [131][256] bf16
        const float* __restrict__ b,
        float* __restrict__ y1, int G) {
    __shared__ unsigned short sW[131 * 256];
    __shared__ float sIn[16][132];
    int tid = threadIdx.x;
    for (int i = tid; i < 131 * 256 / 2; i += 256)
        reinterpret_cast<unsigned*>(sW)[i] = reinterpret_cast<const unsigned*>(W16)[i];
    int g0 = blockIdx.x * 16;
    for (int i = tid; i < 16 * 131; i += 256) {
        int g = i / 131, k = i - g * 131;
        float v = 0.f;
        if (g0 + g < G)
            v = (k < 128) ? gsum[(size_t)(g0 + g) * 128 + k]
                          : fg[(size_t)(g0 + g) * 3 + (k - 128)];
        sIn[g][k] = v;
    }
    __syncthreads();
    float bias = b[tid];
    for (int g = 0; g < 16; ++g) {
        if (g0 + g >= G) break;
        float acc = bias;
        #pragma unroll 8
        for (int k = 0; k < 131; ++k)
            acc += sIn[g][k] * bf2f(sW[k * 256 + tid]);
        y1[(size_t)(g0 + g) * 256 + tid] = selu_f(acc);
    }
}

__global__ __launch_bounds__(256) void mlp2_kernel(
        const float* __restrict__ y1,
        const unsigned short* __restrict__ W16,    // [256][128] bf16
        const float* __restrict__ b,
        float* __restrict__ y2, int G) {
    __shared__ unsigned short sW[256 * 128];
    __shared__ float sIn[16][256];
    int tid = threadIdx.x;
    for (int i = tid; i < 256 * 128 / 2; i += 256)
        reinterpret_cast<unsigned*>(sW)[i] = reinterpret_cast<const unsigned*>(W16)[i];
    int g0 = blockIdx.x * 16;
    for (int i = tid; i < 16 * 256; i += 256) {
        int g = i >> 8, k = i & 255;
        sIn[g][k] = (g0 + g < G) ? y1[(size_t)(g0 + g) * 256 + k] : 0.f;
    }
    __syncthreads();
    int o = tid & 127;
    int half = tid >> 7;
    float bias = b[o];
    for (int gg = 0; gg < 8; ++gg) {
        int g = half * 8 + gg;
        if (g0 + g >= G) break;
        float acc = bias;
        #pragma unroll 8
        for (int k = 0; k < 256; ++k)
            acc += sIn[g][k] * bf2f(sW[k * 128 + o]);
        y2[(size_t)(g0 + g) * 128 + o] = selu_f(acc);
    }
}

__global__ void mlp3_kernel(const float* __restrict__ y2, const float* __restrict__ W,
                            const float* __restrict__ b, float* __restrict__ out, int G) {
    int g = blockIdx.x * blockDim.x + threadIdx.x;
    if (g >= G) return;
    const float* in = y2 + (size_t)g * 128;
    float acc = b[0];
    #pragma unroll 8
    for (int k = 0; k < 128; ++k) acc += in[k] * W[k];
    out[g] = acc;
}

extern "C" void kernel_launch(void* const* d_in, const int* in_sizes, int n_in,
                              void* d_out, int out_size, void* d_ws, size_t ws_size,
                              hipStream_t stream) {
    const float* feats_node  = (const float*)d_in[0];
    const float* feats_graph = (const float*)d_in[1];
    const int*   src         = (const int*)d_in[2];
    const int*   dst         = (const int*)d_in[3];
    const int*   node2graph  = (const int*)d_in[4];
    const float* W1 = (const float*)d_in[5];
    const float* b1 = (const float*)d_in[6];
    const float* W2 = (const float*)d_in[7];
    const float* b2 = (const float*)d_in[8];
    const float* W3 = (const float*)d_in[9];
    const float* b3 = (const float*)d_in[10];
    const float* L1w = (const float*)d_in[11];
    const float* L1b = (const float*)d_in[12];
    const float* L2w = (const float*)d_in[13];
    const float* L2b = (const float*)d_in[14];
    const float* L3w = (const float*)d_in[15];
    const float* L3b = (const float*)d_in[16];

    const int N = in_sizes[0] / 64;
    const int G = in_sizes[1] / 3;
    const int E = in_sizes[2];
    const int NBKT = (N + 255) >> 8;
    const int nmat = NBKT * NBLK;
    const int nscan = 2 * nmat;                      // cntD|cntS concatenated
    const int NBsc = (nscan + SCAN_B - 1) / SCAN_B;

    // ---- workspace layout ----
    int* iws = (int*)d_ws;
    int* deg_out_i = iws;                      // N
    int* deg_in_i  = deg_out_i + N;            // N
    int* row_start = deg_in_i + N;             // N
    int* bsums     = row_start + N;            // NBsc (<=512)
    int* cntD      = bsums + 512;              // nmat  (cntS must follow contiguously)
    int* cntS      = cntD + nmat;              // nmat
    int* csr_src   = cntS + nmat;              // E

    float* norm_out = (float*)(csr_src + E);   // N

    unsigned short* feats16 = (unsigned short*)(norm_out + N);    // [N][64]
    unsigned short* x16     = feats16 + (size_t)N * 64;           // [N][128]  (L1 out, L3 out)
    unsigned short* z16     = x16 + (size_t)N * 128;              // [N][128]  (L2 out)
    unsigned short* Wt1     = z16 + (size_t)N * 128;              // 128*64
    unsigned short* Wt2     = Wt1 + 128 * 64;                     // 128*128
    unsigned short* Wt3     = Wt2 + 128 * 128;                    // 128*128
    unsigned short* L1w16   = Wt3 + 128 * 128;                    // 131*256
    unsigned short* L2w16   = L1w16 + 131 * 256;                  // 256*128

    float* gsum = (float*)(L2w16 + 256 * 128); // G*128
    float* y1   = gsum + (size_t)G * 128;      // G*256
    float* y2   = y1 + (size_t)G * 256;        // G*128

    // pairs/sbuf alias z16 (dead until L2 output; preprocessing finishes first)
    uint2* pairs = (uint2*)(((uintptr_t)z16 + 15) & ~(uintptr_t)15);  // E uint2
    int*   sbuf  = (int*)(pairs + E);                                  // E ints
    int*   sbufm = sbuf - E;   // virtual base: cntS carries +E from concatenated scan

    float* out = (float*)d_out;

    // ---- 1. weight prep (1 dispatch) ----
    {
        const int total = 128 * 64 + 2 * 128 * 128 + 131 * 256 / 4 + 256 * 128 / 4;
        prep_weights_kernel<<<(total + 255) / 256, 256, 0, stream>>>(
            W1, W2, W3, L1w, L2w, Wt1, Wt2, Wt3, L1w16, L2w16);
    }

    // ---- 2. bucket partition: hist + concatenated scan + scatter (5 dispatches) ----
    coarse_hist_kernel<<<NBLK, 256, 0, stream>>>(src, dst, cntD, cntS, E, NBKT);
    scan_block_sums<<<NBsc, 256, 0, stream>>>(cntD, bsums, nscan);
    scan_bsums<<<1, 256, 0, stream>>>(bsums, NBsc);
    scan_apply<<<NBsc, 256, 0, stream>>>(cntD, bsums, cntD, nscan);
    scatter_kernel<<<NBLK, 256, 0, stream>>>(src, dst, cntD, cntS, pairs, sbufm, E, NBKT);

    // ---- 3. fused bucket build: deg_out + CSR (1 dispatch) ----
    bucket_build_kernel<<<NBKT, 256, 0, stream>>>(
        sbufm, pairs, cntD, cntS, deg_out_i, row_start, deg_in_i, csr_src, N, E, NBKT);

    // ---- 4. features -> bf16 prescaled (norm_out inline) (1 dispatch) ----
    cvt_feats_kernel<<<(8 * N + 255) / 256, 256, 0, stream>>>(
        feats_node, deg_out_i, norm_out, feats16, N);

    const int layer_grid = (N + 127) / 128;

    // ---- 5. three fused GCN layers (ping-pong: feats16->x16->z16->x16) ----
    fused_layer_kernel<64, true, true><<<layer_grid, 256, 0, stream>>>(
        feats16, row_start, deg_in_i, csr_src, Wt1, b1, norm_out, x16, N);
    fused_layer_kernel<128, true, true><<<layer_grid, 256, 0, stream>>>(
        x16, row_start, deg_in_i, csr_src, Wt2, b2, norm_out, z16, N);
    fused_layer_kernel<128, false, false><<<layer_grid, 256, 0, stream>>>(
        z16, row_start, deg_in_i, csr_src, Wt3, b3, norm_out, x16, N);

    // ---- 6. readout (binary search inline) ----
    readout_kernel<<<G, 128, 0, stream>>>(x16, node2graph, gsum, N, G);

    // ---- 7. MLP head ----
    mlp1_kernel<<<(G + 15) / 16, 256, 0, stream>>>(gsum, feats_graph, L1w16, L1b, y1, G);
    mlp2_kernel<<<(G + 15) / 16, 256, 0, stream>>>(y1, L2w16, L2b, y2, G);
    mlp3_kernel<<<(G + 255) / 256, 256, 0, stream>>>(y2, L3w, L3b, out, G);
}

// Round 12
// 484.141 us; speedup vs baseline: 1.3123x; 1.3123x over previous
//
#include <hip/hip_runtime.h>
#include <math.h>

#define SELU_ALPHA 1.6732632423543772f
#define SELU_SCALE 1.0507009873554805f

#define NBLK 512          // partition blocks (E divides exactly: 512*3125)
#define MAXBKT 512        // static LDS sizing; actual NBKT = ceil(N/256)

typedef __attribute__((ext_vector_type(8))) short bf16x8;
typedef __attribute__((ext_vector_type(4))) float f32x4;

__device__ __forceinline__ float selu_f(float x) {
    return SELU_SCALE * (x > 0.f ? x : SELU_ALPHA * expm1f(x));
}

__device__ __forceinline__ float bf2f(unsigned short u) {
    return __uint_as_float(((unsigned)u) << 16);
}
__device__ __forceinline__ unsigned short f2bf(float f) {
    unsigned u = __float_as_uint(f);
    unsigned r = (u + 0x7fffu + ((u >> 16) & 1u)) >> 16;
    return (unsigned short)r;
}

// ---- exclusive scan (3 kernels), in-place safe; used on concatenated cntD|cntS ----
#define SCAN_B 1024

__global__ __launch_bounds__(256) void scan_block_sums(const int* __restrict__ in,
                                                       int* __restrict__ bsums, int n) {
    __shared__ int s[256];
    int b = blockIdx.x, t = threadIdx.x;
    int base = b * SCAN_B;
    int sum = 0;
    for (int i = t; i < SCAN_B; i += 256) {
        int idx = base + i;
        sum += (idx < n) ? in[idx] : 0;
    }
    s[t] = sum; __syncthreads();
    for (int off = 128; off > 0; off >>= 1) {
        if (t < off) s[t] += s[t + off];
        __syncthreads();
    }
    if (t == 0) bsums[b] = s[0];
}

__global__ __launch_bounds__(256) void scan_bsums(int* __restrict__ bsums, int nb) {
    __shared__ int s[256];
    __shared__ int carry_s;
    int t = threadIdx.x;
    if (t == 0) carry_s = 0;
    __syncthreads();
    for (int base = 0; base < nb; base += 256) {
        int idx = base + t;
        int v = (idx < nb) ? bsums[idx] : 0;
        s[t] = v; __syncthreads();
        for (int off = 1; off < 256; off <<= 1) {
            int x = (t >= off) ? s[t - off] : 0;
            __syncthreads();
            s[t] += x;
            __syncthreads();
        }
        int incl = s[t];
        int excl = incl - v;
        int c = carry_s;
        __syncthreads();
        if (idx < nb) bsums[idx] = c + excl;
        if (t == 255) carry_s = c + incl;
        __syncthreads();
    }
}

__global__ __launch_bounds__(256) void scan_apply(const int* __restrict__ in,
                                                  const int* __restrict__ boffs,
                                                  int* __restrict__ out, int n) {
    __shared__ int s[256];
    int b = blockIdx.x, t = threadIdx.x;
    int idx0 = b * SCAN_B + t * 4;
    int v[4]; int tsum = 0;
    #pragma unroll
    for (int k = 0; k < 4; ++k) {
        int idx = idx0 + k;
        v[k] = (idx < n) ? in[idx] : 0;
        tsum += v[k];
    }
    s[t] = tsum; __syncthreads();
    for (int off = 1; off < 256; off <<= 1) {
        int x = (t >= off) ? s[t - off] : 0;
        __syncthreads();
        s[t] += x;
        __syncthreads();
    }
    int run = s[t] - tsum + boffs[b];
    #pragma unroll
    for (int k = 0; k < 4; ++k) {
        int idx = idx0 + k;
        if (idx < n) out[idx] = run;
        run += v[k];
    }
}

// ---- K1: per-block coarse histograms of dst>>8 and src>>8 (LDS atomics only) ----
__global__ __launch_bounds__(256) void coarse_hist_kernel(
        const int* __restrict__ src, const int* __restrict__ dst,
        int* __restrict__ cntD, int* __restrict__ cntS, int E, int nbkt) {
    __shared__ int hD[MAXBKT];
    __shared__ int hS[MAXBKT];
    int bb = blockIdx.x, t = threadIdx.x;
    for (int k = t; k < MAXBKT; k += 256) { hD[k] = 0; hS[k] = 0; }
    __syncthreads();
    int chunk = E / NBLK;                 // exact
    int beg = bb * chunk, end = beg + chunk;
    for (int i = beg + t; i < end; i += 256) {
        atomicAdd(&hD[((unsigned)dst[i]) >> 8], 1);
        atomicAdd(&hS[((unsigned)src[i]) >> 8], 1);
    }
    __syncthreads();
    for (int k = t; k < nbkt; k += 256) {
        cntD[k * NBLK + bb] = hD[k];
        cntS[k * NBLK + bb] = hS[k];
    }
}

// ---- K2: scatter. cntS entries carry +E offset (concatenated scan); caller passes
//      sbufm = sbuf - E so writes land correctly. ----
__global__ __launch_bounds__(256) void scatter_kernel(
        const int* __restrict__ src, const int* __restrict__ dst,
        const int* __restrict__ cntD, const int* __restrict__ cntS,
        uint2* __restrict__ pairs, int* __restrict__ sbufm, int E, int nbkt) {
    __shared__ int cD[MAXBKT];
    __shared__ int cS[MAXBKT];
    int bb = blockIdx.x, t = threadIdx.x;
    for (int k = t; k < nbkt; k += 256) {
        cD[k] = cntD[k * NBLK + bb];
        cS[k] = cntS[k * NBLK + bb];
    }
    __syncthreads();
    int chunk = E / NBLK;
    int beg = bb * chunk, end = beg + chunk;
    for (int i = beg + t; i < end; i += 256) {
        unsigned s = (unsigned)src[i], d = (unsigned)dst[i];
        int pD = atomicAdd(&cD[d >> 8], 1);
        pairs[pD] = make_uint2(s, d);
        int pS = atomicAdd(&cS[s >> 8], 1);
        sbufm[pS] = (int)s;
    }
}

// ---- K3: fused bucket build: deg_out histogram + CSR (row_start, deg_in, csr_src) ----
__global__ __launch_bounds__(256) void bucket_build_kernel(
        const int* __restrict__ sbufm, const uint2* __restrict__ pairs,
        const int* __restrict__ cntD, const int* __restrict__ cntS,
        int* __restrict__ deg_out, int* __restrict__ row_start,
        int* __restrict__ deg_in, int* __restrict__ csr_src,
        int N, int E, int nbkt) {
    __shared__ int hist[256];
    __shared__ int sc[256];
    __shared__ int cur[256];
    int b = blockIdx.x, t = threadIdx.x;
    int node = (b << 8) + t;

    // part 1: deg_out from src-bucket values (indices carry +E offset)
    {
        int base = cntS[b * NBLK];
        int end = (b + 1 < nbkt) ? cntS[(b + 1) * NBLK] : 2 * E;
        hist[t] = 0; __syncthreads();
        for (int i = base + t; i < end; i += 256)
            atomicAdd(&hist[sbufm[i] & 255], 1);
        __syncthreads();
        if (node < N) deg_out[node] = hist[t];
        __syncthreads();
    }

    // part 2: CSR build from dst-bucket pairs
    {
        int base = cntD[b * NBLK];
        int end = (b + 1 < nbkt) ? cntD[(b + 1) * NBLK] : E;
        hist[t] = 0; __syncthreads();
        for (int i = base + t; i < end; i += 256)
            atomicAdd(&hist[pairs[i].y & 255], 1);
        __syncthreads();
        int v = hist[t];
        sc[t] = v; __syncthreads();
        for (int off = 1; off < 256; off <<= 1) {
            int x = (t >= off) ? sc[t - off] : 0;
            __syncthreads();
            sc[t] += x;
            __syncthreads();
        }
        int ex = sc[t] - v;
        cur[t] = base + ex;
        if (node < N) { row_start[node] = base + ex; deg_in[node] = v; }
        __syncthreads();
        for (int i = base + t; i < end; i += 256) {
            uint2 p = pairs[i];
            int pos = atomicAdd(&cur[p.y & 255], 1);
            csr_src[pos] = (int)p.x;
        }
    }
}

// ---- prep: all weight conversions in ONE dispatch ----
__global__ void prep_weights_kernel(
        const float* __restrict__ W1, const float* __restrict__ W2,
        const float* __restrict__ W3, const float* __restrict__ L1w,
        const float* __restrict__ L2w,
        unsigned short* __restrict__ Wt1, unsigned short* __restrict__ Wt2,
        unsigned short* __restrict__ Wt3, unsigned short* __restrict__ L1w16,
        unsigned short* __restrict__ L2w16) {
    const int s0 = 128 * 64, s1 = 128 * 128, s2 = 128 * 128;
    const int s3 = 131 * 256 / 4, s4 = 256 * 128 / 4;
    int i = blockIdx.x * 256 + threadIdx.x;
    if (i < s0) {
        int col = i / 64, k = i % 64;
        Wt1[i] = f2bf(W1[k * 128 + col]);
        return;
    }
    i -= s0;
    if (i < s1) {
        int col = i / 128, k = i % 128;
        Wt2[i] = f2bf(W2[k * 128 + col]);
        return;
    }
    i -= s1;
    if (i < s2) {
        int col = i / 128, k = i % 128;
        Wt3[i] = f2bf(W3[k * 128 + col]);
        return;
    }
    i -= s2;
    if (i < s3) {
        float4 v = reinterpret_cast<const float4*>(L1w)[i];
        unsigned short o[4] = { f2bf(v.x), f2bf(v.y), f2bf(v.z), f2bf(v.w) };
        reinterpret_cast<uint2*>(L1w16)[i] = *reinterpret_cast<uint2*>(o);
        return;
    }
    i -= s3;
    if (i < s4) {
        float4 v = reinterpret_cast<const float4*>(L2w)[i];
        unsigned short o[4] = { f2bf(v.x), f2bf(v.y), f2bf(v.z), f2bf(v.w) };
        reinterpret_cast<uint2*>(L2w16)[i] = *reinterpret_cast<uint2*>(o);
    }
}

// ---- prep: feats -> bf16 prescaled by norm_out (computed inline); stores norm_out ----
__global__ void cvt_feats_kernel(const float* __restrict__ feats,
                                 const int* __restrict__ deg_out,
                                 float* __restrict__ norm_out,
                                 unsigned short* __restrict__ outp, int N) {
    int i = blockIdx.x * blockDim.x + threadIdx.x;   // i = n*8 + chunk
    if (i >= 8 * N) return;
    int n = i >> 3, c = i & 7;
    float no = 1.f / sqrtf(fmaxf((float)deg_out[n], 1.f));
    if (c == 0) norm_out[n] = no;
    const float* fp = feats + (size_t)n * 64 + c * 8;
    float4 a = *reinterpret_cast<const float4*>(fp);
    float4 b = *reinterpret_cast<const float4*>(fp + 4);
    unsigned short o[8] = { f2bf(a.x * no), f2bf(a.y * no), f2bf(a.z * no), f2bf(a.w * no),
                            f2bf(b.x * no), f2bf(b.y * no), f2bf(b.z * no), f2bf(b.w * no) };
    *reinterpret_cast<float4*>(outp + (size_t)n * 64 + c * 8) = *reinterpret_cast<float4*>(o);
}

// ---- gather-aggregate with shuffle-broadcast index ILP (norm_in inline) ----
// agg16[n] = f2bf(nin(n) * sum_e x16[csr_src[e]])   (x16 prescaled by norm_out)
template<int TPG, int FIN>   // TPG = FIN/8
__global__ __launch_bounds__(256) void csr_agg_kernel(
        const unsigned short* __restrict__ x, const int* __restrict__ row_start,
        const int* __restrict__ deg_in, const int* __restrict__ csr_src,
        unsigned short* __restrict__ agg, int N) {
    const int GPB = 256 / TPG;
    int g = threadIdx.x / TPG;
    int j = threadIdx.x % TPG;
    int n = blockIdx.x * GPB + g;
    if (n >= N) return;
    const int lane = threadIdx.x & 63;
    const int gbase = lane & ~(TPG - 1);   // group base lane within wave
    int beg = row_start[n];
    int dg = deg_in[n];
    int end = beg + dg;
    float nin = 1.f / sqrtf(fmaxf((float)dg, 1.f));
    float acc[8] = {0.f, 0.f, 0.f, 0.f, 0.f, 0.f, 0.f, 0.f};
    for (int c = beg; c < end; c += TPG) {
        int myIdx = (c + j < end) ? csr_src[c + j] : 0;
        int cnt = end - c;                 // uniform within group
        float4 v[TPG];
        #pragma unroll
        for (int t = 0; t < TPG; ++t) {
            if (t < cnt) {
                int s = __shfl(myIdx, gbase + t, 64);
                v[t] = *reinterpret_cast<const float4*>(&x[(size_t)s * FIN + j * 8]);
            }
        }
        #pragma unroll
        for (int t = 0; t < TPG; ++t) {
            if (t < cnt) {
                const unsigned short* u = reinterpret_cast<const unsigned short*>(&v[t]);
                #pragma unroll
                for (int k = 0; k < 8; ++k) acc[k] += bf2f(u[k]);
            }
        }
    }
    unsigned short ov[8];
    #pragma unroll
    for (int k = 0; k < 8; ++k) ov[k] = f2bf(acc[k] * nin);
    *reinterpret_cast<float4*>(&agg[(size_t)n * FIN + j * 8]) = *reinterpret_cast<float4*>(ov);
}

// ---- MFMA node GEMM (128x128 tile, 4 waves, 16x16x32 bf16) ----
// out[n][col] = act(agg16[n] @ Wt^T + b) [* norm_out[n] if SCALE_OUT], bf16 row-major.
template<int FIN, bool SELU, bool SCALE_OUT>
__global__ __launch_bounds__(256, 2) void gemm_mfma_kernel(
        const unsigned short* __restrict__ agg16,  // [N][FIN] bf16
        const unsigned short* __restrict__ Wt,     // [128][FIN] bf16
        const float* __restrict__ b,
        const float* __restrict__ norm_out,
        unsigned short* __restrict__ out,          // [N][128] bf16
        int N) {
    const int PAD = 8;
    const int LDA = FIN + PAD;
    const int CH = FIN / 8;
    __shared__ unsigned short sA[128 * LDA];
    __shared__ unsigned short sW[128 * LDA];
    const int tid = threadIdx.x;
    const int wave = tid >> 6, lane = tid & 63;
    const int wr = (wave >> 1) * 64;
    const int wc = (wave & 1) * 64;
    const int n0 = blockIdx.x * 128;

    for (int i = tid; i < 128 * CH; i += 256) {
        int col = i / CH, kc = i % CH;
        *reinterpret_cast<float4*>(&sW[col * LDA + kc * 8]) =
            *reinterpret_cast<const float4*>(&Wt[col * FIN + kc * 8]);
    }
    for (int i = tid; i < 128 * CH; i += 256) {
        int node = i / CH, kc = i % CH;
        int n = n0 + node;
        float4 v = make_float4(0.f, 0.f, 0.f, 0.f);
        if (n < N)
            v = *reinterpret_cast<const float4*>(&agg16[(size_t)n * FIN + kc * 8]);
        *reinterpret_cast<float4*>(&sA[node * LDA + kc * 8]) = v;
    }
    __syncthreads();

    const int l16 = lane & 15;
    const int lk = (lane >> 4) * 8;
    f32x4 acc[4][4];
    #pragma unroll
    for (int mi = 0; mi < 4; ++mi)
        #pragma unroll
        for (int ci = 0; ci < 4; ++ci)
            acc[mi][ci] = (f32x4){0.f, 0.f, 0.f, 0.f};

    #pragma unroll
    for (int k0 = 0; k0 < FIN; k0 += 32) {
        bf16x8 a[4], w[4];
        #pragma unroll
        for (int mi = 0; mi < 4; ++mi)
            a[mi] = *reinterpret_cast<const bf16x8*>(&sA[(wr + mi * 16 + l16) * LDA + k0 + lk]);
        #pragma unroll
        for (int ci = 0; ci < 4; ++ci)
            w[ci] = *reinterpret_cast<const bf16x8*>(&sW[(wc + ci * 16 + l16) * LDA + k0 + lk]);
        #pragma unroll
        for (int mi = 0; mi < 4; ++mi)
            #pragma unroll
            for (int ci = 0; ci < 4; ++ci)
                acc[mi][ci] = __builtin_amdgcn_mfma_f32_16x16x32_bf16(
                    a[mi], w[ci], acc[mi][ci], 0, 0, 0);
    }

    // D frag: col = lane&15, row = (lane>>4)*4 + r
    const int rbase = (lane >> 4) * 4;
    #pragma unroll
    for (int ci = 0; ci < 4; ++ci) {
        int col = wc + ci * 16 + l16;
        float bias = b[col];
        #pragma unroll
        for (int mi = 0; mi < 4; ++mi) {
            #pragma unroll
            for (int r = 0; r < 4; ++r) {
                int n = n0 + wr + mi * 16 + rbase + r;
                if (n < N) {
                    float v = acc[mi][ci][r] + bias;
                    if (SELU) v = selu_f(v);
                    if (SCALE_OUT) v *= norm_out[n];
                    out[(size_t)n * 128 + col] = f2bf(v);
                }
            }
        }
    }
}

// ---- readout with inline binary search (node2graph sorted) ----
__global__ __launch_bounds__(128) void readout_kernel(
        const unsigned short* __restrict__ y, const int* __restrict__ n2g,
        float* __restrict__ gsum, int N, int G) {
    int g = blockIdx.x;
    int o = threadIdx.x;
    if (g >= G) return;
    int beg, end;
    {
        int lo = 0, hi = N;
        while (lo < hi) { int m = (lo + hi) >> 1; if (n2g[m] < g) lo = m + 1; else hi = m; }
        beg = lo;
        lo = beg; hi = N;
        while (lo < hi) { int m = (lo + hi) >> 1; if (n2g[m] < g + 1) lo = m + 1; else hi = m; }
        end = lo;
    }
    float acc = 0.f;
    for (int n = beg; n < end; ++n)
        acc += bf2f(y[(size_t)n * 128 + o]);
    gsum[(size_t)g * 128 + o] = acc;
}

// ---- MLP head: 16 graphs per block, bf16 W staged in LDS, fp32 accumulate ----
__global__ __launch_bounds__(256) void mlp1_kernel(
        const float* __restrict__ gsum, const float* __restrict__ fg,
        const unsigned short* __restrict__ W16,    // [131][256] bf16
        const float* __restrict__ b,
        float* __restrict__ y1, int G) {
    __shared__ unsigned short sW[131 * 256];
    __shared__ float sIn[16][132];
    int tid = threadIdx.x;
    for (int i = tid; i < 131 * 256 / 2; i += 256)
        reinterpret_cast<unsigned*>(sW)[i] = reinterpret_cast<const unsigned*>(W16)[i];
    int g0 = blockIdx.x * 16;
    for (int i = tid; i < 16 * 131; i += 256) {
        int g = i / 131, k = i - g * 131;
        float v = 0.f;
        if (g0 + g < G)
            v = (k < 128) ? gsum[(size_t)(g0 + g) * 128 + k]
                          : fg[(size_t)(g0 + g) * 3 + (k - 128)];
        sIn[g][k] = v;
    }
    __syncthreads();
    float bias = b[tid];
    for (int g = 0; g < 16; ++g) {
        if (g0 + g >= G) break;
        float acc = bias;
        #pragma unroll 8
        for (int k = 0; k < 131; ++k)
            acc += sIn[g][k] * bf2f(sW[k * 256 + tid]);
        y1[(size_t)(g0 + g) * 256 + tid] = selu_f(acc);
    }
}

__global__ __launch_bounds__(256) void mlp2_kernel(
        const float* __restrict__ y1,
        const unsigned short* __restrict__ W16,    // [256][128] bf16
        const float* __restrict__ b,
        float* __restrict__ y2, int G) {
    __shared__ unsigned short sW[256 * 128];
    __shared__ float sIn[16][256];
    int tid = threadIdx.x;
    for (int i = tid; i < 256 * 128 / 2; i += 256)
        reinterpret_cast<unsigned*>(sW)[i] = reinterpret_cast<const unsigned*>(W16)[i];
    int g0 = blockIdx.x * 16;
    for (int i = tid; i < 16 * 256; i += 256) {
        int g = i >> 8, k = i & 255;
        sIn[g][k] = (g0 + g < G) ? y1[(size_t)(g0 + g) * 256 + k] : 0.f;
    }
    __syncthreads();
    int o = tid & 127;
    int half = tid >> 7;
    float bias = b[o];
    for (int gg = 0; gg < 8; ++gg) {
        int g = half * 8 + gg;
        if (g0 + g >= G) break;
        float acc = bias;
        #pragma unroll 8
        for (int k = 0; k < 256; ++k)
            acc += sIn[g][k] * bf2f(sW[k * 128 + o]);
        y2[(size_t)(g0 + g) * 128 + o] = selu_f(acc);
    }
}

__global__ void mlp3_kernel(const float* __restrict__ y2, const float* __restrict__ W,
                            const float* __restrict__ b, float* __restrict__ out, int G) {
    int g = blockIdx.x * blockDim.x + threadIdx.x;
    if (g >= G) return;
    const float* in = y2 + (size_t)g * 128;
    float acc = b[0];
    #pragma unroll 8
    for (int k = 0; k < 128; ++k) acc += in[k] * W[k];
    out[g] = acc;
}

extern "C" void kernel_launch(void* const* d_in, const int* in_sizes, int n_in,
                              void* d_out, int out_size, void* d_ws, size_t ws_size,
                              hipStream_t stream) {
    const float* feats_node  = (const float*)d_in[0];
    const float* feats_graph = (const float*)d_in[1];
    const int*   src         = (const int*)d_in[2];
    const int*   dst         = (const int*)d_in[3];
    const int*   node2graph  = (const int*)d_in[4];
    const float* W1 = (const float*)d_in[5];
    const float* b1 = (const float*)d_in[6];
    const float* W2 = (const float*)d_in[7];
    const float* b2 = (const float*)d_in[8];
    const float* W3 = (const float*)d_in[9];
    const float* b3 = (const float*)d_in[10];
    const float* L1w = (const float*)d_in[11];
    const float* L1b = (const float*)d_in[12];
    const float* L2w = (const float*)d_in[13];
    const float* L2b = (const float*)d_in[14];
    const float* L3w = (const float*)d_in[15];
    const float* L3b = (const float*)d_in[16];

    const int N = in_sizes[0] / 64;
    const int G = in_sizes[1] / 3;
    const int E = in_sizes[2];
    const int NBKT = (N + 255) >> 8;
    const int nmat = NBKT * NBLK;
    const int nscan = 2 * nmat;                      // cntD|cntS concatenated
    const int NBsc = (nscan + SCAN_B - 1) / SCAN_B;

    // ---- workspace layout ----
    int* iws = (int*)d_ws;
    int* deg_out_i = iws;                      // N
    int* deg_in_i  = deg_out_i + N;            // N
    int* row_start = deg_in_i + N;             // N
    int* bsums     = row_start + N;            // NBsc (<=512)
    int* cntD      = bsums + 512;              // nmat  (cntS must follow contiguously)
    int* cntS      = cntD + nmat;              // nmat
    int* csr_src   = cntS + nmat;              // E

    float* norm_out = (float*)(csr_src + E);   // N

    unsigned short* feats16 = (unsigned short*)(norm_out + N);    // [N][64]
    unsigned short* x16     = feats16 + (size_t)N * 64;           // [N][128]
    unsigned short* agg16   = x16 + (size_t)N * 128;              // [N][128]
    unsigned short* y16     = agg16 + (size_t)N * 128;            // [N][128]
    unsigned short* Wt1     = y16 + (size_t)N * 128;              // 128*64
    unsigned short* Wt2     = Wt1 + 128 * 64;                     // 128*128
    unsigned short* Wt3     = Wt2 + 128 * 128;                    // 128*128
    unsigned short* L1w16   = Wt3 + 128 * 128;                    // 131*256
    unsigned short* L2w16   = L1w16 + 131 * 256;                  // 256*128

    float* gsum = (float*)(L2w16 + 256 * 128); // G*128
    float* y1   = gsum + (size_t)G * 128;      // G*256
    float* y2   = y1 + (size_t)G * 256;        // G*128

    // pairs/sbuf alias y16 (dead until layer-3 GEMM output; preprocessing finishes first)
    uint2* pairs = (uint2*)(((uintptr_t)y16 + 15) & ~(uintptr_t)15);  // E uint2
    int*   sbuf  = (int*)(pairs + E);                                  // E ints
    int*   sbufm = sbuf - E;   // virtual base: cntS carries +E from concatenated scan

    float* out = (float*)d_out;

    // ---- 1. weight prep (1 dispatch) ----
    {
        const int total = 128 * 64 + 2 * 128 * 128 + 131 * 256 / 4 + 256 * 128 / 4;
        prep_weights_kernel<<<(total + 255) / 256, 256, 0, stream>>>(
            W1, W2, W3, L1w, L2w, Wt1, Wt2, Wt3, L1w16, L2w16);
    }

    // ---- 2. bucket partition: hist + concatenated scan + scatter (5 dispatches) ----
    coarse_hist_kernel<<<NBLK, 256, 0, stream>>>(src, dst, cntD, cntS, E, NBKT);
    scan_block_sums<<<NBsc, 256, 0, stream>>>(cntD, bsums, nscan);
    scan_bsums<<<1, 256, 0, stream>>>(bsums, NBsc);
    scan_apply<<<NBsc, 256, 0, stream>>>(cntD, bsums, cntD, nscan);
    scatter_kernel<<<NBLK, 256, 0, stream>>>(src, dst, cntD, cntS, pairs, sbufm, E, NBKT);

    // ---- 3. fused bucket build: deg_out + CSR (1 dispatch) ----
    bucket_build_kernel<<<NBKT, 256, 0, stream>>>(
        sbufm, pairs, cntD, cntS, deg_out_i, row_start, deg_in_i, csr_src, N, E, NBKT);

    // ---- 4. features -> bf16 prescaled (norm_out inline) (1 dispatch) ----
    cvt_feats_kernel<<<(8 * N + 255) / 256, 256, 0, stream>>>(
        feats_node, deg_out_i, norm_out, feats16, N);

    const int gemm_grid = (N + 127) / 128;

    // ---- 5. layer 1 (FIN=64) ----
    csr_agg_kernel<8, 64><<<(N + 31) / 32, 256, 0, stream>>>(
        feats16, row_start, deg_in_i, csr_src, agg16, N);
    gemm_mfma_kernel<64, true, true><<<gemm_grid, 256, 0, stream>>>(
        agg16, Wt1, b1, norm_out, x16, N);

    // ---- 6. layer 2 (FIN=128) ----
    csr_agg_kernel<16, 128><<<(N + 15) / 16, 256, 0, stream>>>(
        x16, row_start, deg_in_i, csr_src, agg16, N);
    gemm_mfma_kernel<128, true, true><<<gemm_grid, 256, 0, stream>>>(
        agg16, Wt2, b2, norm_out, x16, N);

    // ---- 7. layer 3 (FIN=128, no selu, unscaled out for readout) ----
    csr_agg_kernel<16, 128><<<(N + 15) / 16, 256, 0, stream>>>(
        x16, row_start, deg_in_i, csr_src, agg16, N);
    gemm_mfma_kernel<128, false, false><<<gemm_grid, 256, 0, stream>>>(
        agg16, Wt3, b3, norm_out, y16, N);

    // ---- 8. readout (binary search inline) ----
    readout_kernel<<<G, 128, 0, stream>>>(y16, node2graph, gsum, N, G);

    // ---- 9. MLP head ----
    mlp1_kernel<<<(G + 15) / 16, 256, 0, stream>>>(gsum, feats_graph, L1w16, L1b, y1, G);
    mlp2_kernel<<<(G + 15) / 16, 256, 0, stream>>>(y1, L2w16, L2b, y2, G);
    mlp3_kernel<<<(G + 255) / 256, 256, 0, stream>>>(y2, L3w, L3b, out, G);
}

// Round 13
// 458.584 us; speedup vs baseline: 1.3855x; 1.0557x over previous
//
#include <hip/hip_runtime.h>
#include <math.h>

#define SELU_ALPHA 1.6732632423543772f
#define SELU_SCALE 1.0507009873554805f

#define NBLK 512          // partition blocks (E divides exactly: 512*3125)
#define MAXBKT 512        // static LDS sizing; actual NBKT = ceil(N/256)

typedef __attribute__((ext_vector_type(8))) short bf16x8;
typedef __attribute__((ext_vector_type(4))) float f32x4;

__device__ __forceinline__ float selu_f(float x) {
    return SELU_SCALE * (x > 0.f ? x : SELU_ALPHA * expm1f(x));
}

__device__ __forceinline__ float bf2f(unsigned short u) {
    return __uint_as_float(((unsigned)u) << 16);
}
__device__ __forceinline__ unsigned short f2bf(float f) {
    unsigned u = __float_as_uint(f);
    unsigned r = (u + 0x7fffu + ((u >> 16) & 1u)) >> 16;
    return (unsigned short)r;
}

// ---- exclusive scan (3 kernels), in-place safe; used on concatenated cntD|cntS ----
#define SCAN_B 1024

__global__ __launch_bounds__(256) void scan_block_sums(const int* __restrict__ in,
                                                       int* __restrict__ bsums, int n) {
    __shared__ int s[256];
    int b = blockIdx.x, t = threadIdx.x;
    int base = b * SCAN_B;
    int sum = 0;
    for (int i = t; i < SCAN_B; i += 256) {
        int idx = base + i;
        sum += (idx < n) ? in[idx] : 0;
    }
    s[t] = sum; __syncthreads();
    for (int off = 128; off > 0; off >>= 1) {
        if (t < off) s[t] += s[t + off];
        __syncthreads();
    }
    if (t == 0) bsums[b] = s[0];
}

__global__ __launch_bounds__(256) void scan_bsums(int* __restrict__ bsums, int nb) {
    __shared__ int s[256];
    __shared__ int carry_s;
    int t = threadIdx.x;
    if (t == 0) carry_s = 0;
    __syncthreads();
    for (int base = 0; base < nb; base += 256) {
        int idx = base + t;
        int v = (idx < nb) ? bsums[idx] : 0;
        s[t] = v; __syncthreads();
        for (int off = 1; off < 256; off <<= 1) {
            int x = (t >= off) ? s[t - off] : 0;
            __syncthreads();
            s[t] += x;
            __syncthreads();
        }
        int incl = s[t];
        int excl = incl - v;
        int c = carry_s;
        __syncthreads();
        if (idx < nb) bsums[idx] = c + excl;
        if (t == 255) carry_s = c + incl;
        __syncthreads();
    }
}

__global__ __launch_bounds__(256) void scan_apply(const int* __restrict__ in,
                                                  const int* __restrict__ boffs,
                                                  int* __restrict__ out, int n) {
    __shared__ int s[256];
    int b = blockIdx.x, t = threadIdx.x;
    int idx0 = b * SCAN_B + t * 4;
    int v[4]; int tsum = 0;
    #pragma unroll
    for (int k = 0; k < 4; ++k) {
        int idx = idx0 + k;
        v[k] = (idx < n) ? in[idx] : 0;
        tsum += v[k];
    }
    s[t] = tsum; __syncthreads();
    for (int off = 1; off < 256; off <<= 1) {
        int x = (t >= off) ? s[t - off] : 0;
        __syncthreads();
        s[t] += x;
        __syncthreads();
    }
    int run = s[t] - tsum + boffs[b];
    #pragma unroll
    for (int k = 0; k < 4; ++k) {
        int idx = idx0 + k;
        if (idx < n) out[idx] = run;
        run += v[k];
    }
}

// ---- K1: per-block coarse histograms of dst>>8 and src>>8 (LDS atomics only) ----
__global__ __launch_bounds__(256) void coarse_hist_kernel(
        const int* __restrict__ src, const int* __restrict__ dst,
        int* __restrict__ cntD, int* __restrict__ cntS, int E, int nbkt) {
    __shared__ int hD[MAXBKT];
    __shared__ int hS[MAXBKT];
    int bb = blockIdx.x, t = threadIdx.x;
    for (int k = t; k < MAXBKT; k += 256) { hD[k] = 0; hS[k] = 0; }
    __syncthreads();
    int chunk = E / NBLK;                 // exact
    int beg = bb * chunk, end = beg + chunk;
    for (int i = beg + t; i < end; i += 256) {
        atomicAdd(&hD[((unsigned)dst[i]) >> 8], 1);
        atomicAdd(&hS[((unsigned)src[i]) >> 8], 1);
    }
    __syncthreads();
    for (int k = t; k < nbkt; k += 256) {
        cntD[k * NBLK + bb] = hD[k];
        cntS[k * NBLK + bb] = hS[k];
    }
}

// ---- K2: scatter. cntS entries carry +E offset (concatenated scan); caller passes
//      sbufm = sbuf - E so writes land correctly. ----
__global__ __launch_bounds__(256) void scatter_kernel(
        const int* __restrict__ src, const int* __restrict__ dst,
        const int* __restrict__ cntD, const int* __restrict__ cntS,
        uint2* __restrict__ pairs, int* __restrict__ sbufm, int E, int nbkt) {
    __shared__ int cD[MAXBKT];
    __shared__ int cS[MAXBKT];
    int bb = blockIdx.x, t = threadIdx.x;
    for (int k = t; k < nbkt; k += 256) {
        cD[k] = cntD[k * NBLK + bb];
        cS[k] = cntS[k * NBLK + bb];
    }
    __syncthreads();
    int chunk = E / NBLK;
    int beg = bb * chunk, end = beg + chunk;
    for (int i = beg + t; i < end; i += 256) {
        unsigned s = (unsigned)src[i], d = (unsigned)dst[i];
        int pD = atomicAdd(&cD[d >> 8], 1);
        pairs[pD] = make_uint2(s, d);
        int pS = atomicAdd(&cS[s >> 8], 1);
        sbufm[pS] = (int)s;
    }
}

// ---- K3: fused bucket build: deg_out histogram + CSR (row_start, deg_in, csr_src) ----
__global__ __launch_bounds__(256) void bucket_build_kernel(
        const int* __restrict__ sbufm, const uint2* __restrict__ pairs,
        const int* __restrict__ cntD, const int* __restrict__ cntS,
        int* __restrict__ deg_out, int* __restrict__ row_start,
        int* __restrict__ deg_in, int* __restrict__ csr_src,
        int N, int E, int nbkt) {
    __shared__ int hist[256];
    __shared__ int sc[256];
    __shared__ int cur[256];
    int b = blockIdx.x, t = threadIdx.x;
    int node = (b << 8) + t;

    // part 1: deg_out from src-bucket values (indices carry +E offset)
    {
        int base = cntS[b * NBLK];
        int end = (b + 1 < nbkt) ? cntS[(b + 1) * NBLK] : 2 * E;
        hist[t] = 0; __syncthreads();
        for (int i = base + t; i < end; i += 256)
            atomicAdd(&hist[sbufm[i] & 255], 1);
        __syncthreads();
        if (node < N) deg_out[node] = hist[t];
        __syncthreads();
    }

    // part 2: CSR build from dst-bucket pairs
    {
        int base = cntD[b * NBLK];
        int end = (b + 1 < nbkt) ? cntD[(b + 1) * NBLK] : E;
        hist[t] = 0; __syncthreads();
        for (int i = base + t; i < end; i += 256)
            atomicAdd(&hist[pairs[i].y & 255], 1);
        __syncthreads();
        int v = hist[t];
        sc[t] = v; __syncthreads();
        for (int off = 1; off < 256; off <<= 1) {
            int x = (t >= off) ? sc[t - off] : 0;
            __syncthreads();
            sc[t] += x;
            __syncthreads();
        }
        int ex = sc[t] - v;
        cur[t] = base + ex;
        if (node < N) { row_start[node] = base + ex; deg_in[node] = v; }
        __syncthreads();
        for (int i = base + t; i < end; i += 256) {
            uint2 p = pairs[i];
            int pos = atomicAdd(&cur[p.y & 255], 1);
            csr_src[pos] = (int)p.x;
        }
    }
}

// ---- prep: all weight conversions in ONE dispatch ----
__global__ void prep_weights_kernel(
        const float* __restrict__ W1, const float* __restrict__ W2,
        const float* __restrict__ W3, const float* __restrict__ L1w,
        const float* __restrict__ L2w,
        unsigned short* __restrict__ Wt1, unsigned short* __restrict__ Wt2,
        unsigned short* __restrict__ Wt3, unsigned short* __restrict__ L1w16,
        unsigned short* __restrict__ L2w16) {
    const int s0 = 128 * 64, s1 = 128 * 128, s2 = 128 * 128;
    const int s3 = 131 * 256 / 4, s4 = 256 * 128 / 4;
    int i = blockIdx.x * 256 + threadIdx.x;
    if (i < s0) {
        int col = i / 64, k = i % 64;
        Wt1[i] = f2bf(W1[k * 128 + col]);
        return;
    }
    i -= s0;
    if (i < s1) {
        int col = i / 128, k = i % 128;
        Wt2[i] = f2bf(W2[k * 128 + col]);
        return;
    }
    i -= s1;
    if (i < s2) {
        int col = i / 128, k = i % 128;
        Wt3[i] = f2bf(W3[k * 128 + col]);
        return;
    }
    i -= s2;
    if (i < s3) {
        float4 v = reinterpret_cast<const float4*>(L1w)[i];
        unsigned short o[4] = { f2bf(v.x), f2bf(v.y), f2bf(v.z), f2bf(v.w) };
        reinterpret_cast<uint2*>(L1w16)[i] = *reinterpret_cast<uint2*>(o);
        return;
    }
    i -= s3;
    if (i < s4) {
        float4 v = reinterpret_cast<const float4*>(L2w)[i];
        unsigned short o[4] = { f2bf(v.x), f2bf(v.y), f2bf(v.z), f2bf(v.w) };
        reinterpret_cast<uint2*>(L2w16)[i] = *reinterpret_cast<uint2*>(o);
    }
}

// ---- prep: feats -> bf16 prescaled by norm_out (computed inline); stores norm_out ----
__global__ void cvt_feats_kernel(const float* __restrict__ feats,
                                 const int* __restrict__ deg_out,
                                 float* __restrict__ norm_out,
                                 unsigned short* __restrict__ outp, int N) {
    int i = blockIdx.x * blockDim.x + threadIdx.x;   // i = n*8 + chunk
    if (i >= 8 * N) return;
    int n = i >> 3, c = i & 7;
    float no = 1.f / sqrtf(fmaxf((float)deg_out[n], 1.f));
    if (c == 0) norm_out[n] = no;
    const float* fp = feats + (size_t)n * 64 + c * 8;
    float4 a = *reinterpret_cast<const float4*>(fp);
    float4 b = *reinterpret_cast<const float4*>(fp + 4);
    unsigned short o[8] = { f2bf(a.x * no), f2bf(a.y * no), f2bf(a.z * no), f2bf(a.w * no),
                            f2bf(b.x * no), f2bf(b.y * no), f2bf(b.z * no), f2bf(b.w * no) };
    *reinterpret_cast<float4*>(outp + (size_t)n * 64 + c * 8) = *reinterpret_cast<float4*>(o);
}

// ---- gather-aggregate with shuffle-broadcast index ILP (norm_in inline) ----
// agg16[n] = f2bf(nin(n) * sum_e x16[csr_src[e]])   (x16 prescaled by norm_out)
template<int TPG, int FIN>   // TPG = FIN/8
__global__ __launch_bounds__(256) void csr_agg_kernel(
        const unsigned short* __restrict__ x, const int* __restrict__ row_start,
        const int* __restrict__ deg_in, const int* __restrict__ csr_src,
        unsigned short* __restrict__ agg, int N) {
    const int GPB = 256 / TPG;
    int g = threadIdx.x / TPG;
    int j = threadIdx.x % TPG;
    int n = blockIdx.x * GPB + g;
    if (n >= N) return;
    const int lane = threadIdx.x & 63;
    const int gbase = lane & ~(TPG - 1);   // group base lane within wave
    int beg = row_start[n];
    int dg = deg_in[n];
    int end = beg + dg;
    float nin = 1.f / sqrtf(fmaxf((float)dg, 1.f));
    float acc[8] = {0.f, 0.f, 0.f, 0.f, 0.f, 0.f, 0.f, 0.f};
    for (int c = beg; c < end; c += TPG) {
        int myIdx = (c + j < end) ? csr_src[c + j] : 0;
        int cnt = end - c;                 // uniform within group
        float4 v[TPG];
        #pragma unroll
        for (int t = 0; t < TPG; ++t) {
            if (t < cnt) {
                int s = __shfl(myIdx, gbase + t, 64);
                v[t] = *reinterpret_cast<const float4*>(&x[(size_t)s * FIN + j * 8]);
            }
        }
        #pragma unroll
        for (int t = 0; t < TPG; ++t) {
            if (t < cnt) {
                const unsigned short* u = reinterpret_cast<const unsigned short*>(&v[t]);
                #pragma unroll
                for (int k = 0; k < 8; ++k) acc[k] += bf2f(u[k]);
            }
        }
    }
    unsigned short ov[8];
    #pragma unroll
    for (int k = 0; k < 8; ++k) ov[k] = f2bf(acc[k] * nin);
    *reinterpret_cast<float4*>(&agg[(size_t)n * FIN + j * 8]) = *reinterpret_cast<float4*>(ov);
}

// ---- MFMA node GEMM: W in LDS only (34.8KB -> 4 blocks/CU), A streamed from global ----
// out[n][col] = act(agg16[n] @ Wt^T + b) [* norm_out[n] if SCALE_OUT], bf16 row-major.
template<int FIN, bool SELU, bool SCALE_OUT>
__global__ __launch_bounds__(256, 4) void gemm_mfma_kernel(
        const unsigned short* __restrict__ agg16,  // [N][FIN] bf16
        const unsigned short* __restrict__ Wt,     // [128][FIN] bf16
        const float* __restrict__ b,
        const float* __restrict__ norm_out,
        unsigned short* __restrict__ out,          // [N][128] bf16
        int N) {
    const int PAD = 8;
    const int LDW = FIN + PAD;
    const int CH = FIN / 8;
    __shared__ unsigned short sW[128 * LDW];
    const int tid = threadIdx.x;
    const int wave = tid >> 6, lane = tid & 63;
    const int wr = (wave >> 1) * 64;
    const int wc = (wave & 1) * 64;
    const int n0 = blockIdx.x * 128;

    for (int i = tid; i < 128 * CH; i += 256) {
        int col = i / CH, kc = i % CH;
        *reinterpret_cast<float4*>(&sW[col * LDW + kc * 8]) =
            *reinterpret_cast<const float4*>(&Wt[col * FIN + kc * 8]);
    }
    __syncthreads();

    const int l16 = lane & 15;
    const int lk = (lane >> 4) * 8;
    const bf16x8 zero8 = (bf16x8){0,0,0,0,0,0,0,0};
    f32x4 acc[4][4];
    #pragma unroll
    for (int mi = 0; mi < 4; ++mi)
        #pragma unroll
        for (int ci = 0; ci < 4; ++ci)
            acc[mi][ci] = (f32x4){0.f, 0.f, 0.f, 0.f};

    #pragma unroll
    for (int k0 = 0; k0 < FIN; k0 += 32) {
        bf16x8 a[4], w[4];
        #pragma unroll
        for (int mi = 0; mi < 4; ++mi) {
            int n = n0 + wr + mi * 16 + l16;
            a[mi] = (n < N)
                ? *reinterpret_cast<const bf16x8*>(&agg16[(size_t)n * FIN + k0 + lk])
                : zero8;
        }
        #pragma unroll
        for (int ci = 0; ci < 4; ++ci)
            w[ci] = *reinterpret_cast<const bf16x8*>(&sW[(wc + ci * 16 + l16) * LDW + k0 + lk]);
        #pragma unroll
        for (int mi = 0; mi < 4; ++mi)
            #pragma unroll
            for (int ci = 0; ci < 4; ++ci)
                acc[mi][ci] = __builtin_amdgcn_mfma_f32_16x16x32_bf16(
                    a[mi], w[ci], acc[mi][ci], 0, 0, 0);
    }

    // D frag: col = lane&15, row = (lane>>4)*4 + r
    const int rbase = (lane >> 4) * 4;
    #pragma unroll
    for (int ci = 0; ci < 4; ++ci) {
        int col = wc + ci * 16 + l16;
        float bias = b[col];
        #pragma unroll
        for (int mi = 0; mi < 4; ++mi) {
            #pragma unroll
            for (int r = 0; r < 4; ++r) {
                int n = n0 + wr + mi * 16 + rbase + r;
                if (n < N) {
                    float v = acc[mi][ci][r] + bias;
                    if (SELU) v = selu_f(v);
                    if (SCALE_OUT) v *= norm_out[n];
                    out[(size_t)n * 128 + col] = f2bf(v);
                }
            }
        }
    }
}

// ---- MLP layer 1 with FUSED readout: per block, 16 graphs ----
// Phase A: 16 threads/graph sum that graph's y16 rows (coalesced 256B reads, fp32,
// same serial order as before) -> sIn. Phase B: dense [16,131]x[131,256] + selu.
__global__ __launch_bounds__(256) void mlp1_kernel(
        const unsigned short* __restrict__ y16,    // [N][128] bf16
        const int* __restrict__ n2g,               // [N] sorted
        const float* __restrict__ fg,              // [G][3]
        const unsigned short* __restrict__ W16,    // [131][256] bf16
        const float* __restrict__ b,
        float* __restrict__ y1, int N, int G) {
    __shared__ unsigned short sW[131 * 256];
    __shared__ float sIn[16][132];
    int tid = threadIdx.x;
    for (int i = tid; i < 131 * 256 / 2; i += 256)
        reinterpret_cast<unsigned*>(sW)[i] = reinterpret_cast<const unsigned*>(W16)[i];

    int grp = tid >> 4;         // graph within block
    int l16 = tid & 15;         // 8-col slice
    int g = blockIdx.x * 16 + grp;
    float a8[8] = {0.f, 0.f, 0.f, 0.f, 0.f, 0.f, 0.f, 0.f};
    if (g < G) {
        int beg, end;
        {
            int lo = 0, hi = N;
            while (lo < hi) { int m = (lo + hi) >> 1; if (n2g[m] < g) lo = m + 1; else hi = m; }
            beg = lo;
            lo = beg; hi = N;
            while (lo < hi) { int m = (lo + hi) >> 1; if (n2g[m] < g + 1) lo = m + 1; else hi = m; }
            end = lo;
        }
        for (int n = beg; n < end; ++n) {
            float4 raw = *reinterpret_cast<const float4*>(&y16[(size_t)n * 128 + l16 * 8]);
            const unsigned short* u = reinterpret_cast<const unsigned short*>(&raw);
            #pragma unroll
            for (int k = 0; k < 8; ++k) a8[k] += bf2f(u[k]);
        }
    }
    #pragma unroll
    for (int k = 0; k < 8; ++k) sIn[grp][l16 * 8 + k] = a8[k];
    if (l16 == 0) {
        if (g < G) {
            sIn[grp][128] = fg[(size_t)g * 3 + 0];
            sIn[grp][129] = fg[(size_t)g * 3 + 1];
            sIn[grp][130] = fg[(size_t)g * 3 + 2];
        } else {
            sIn[grp][128] = 0.f; sIn[grp][129] = 0.f; sIn[grp][130] = 0.f;
        }
    }
    __syncthreads();

    int g0 = blockIdx.x * 16;
    float bias = b[tid];
    for (int gg = 0; gg < 16; ++gg) {
        if (g0 + gg >= G) break;
        float acc = bias;
        #pragma unroll 8
        for (int k = 0; k < 131; ++k)
            acc += sIn[gg][k] * bf2f(sW[k * 256 + tid]);
        y1[(size_t)(g0 + gg) * 256 + tid] = selu_f(acc);
    }
}

__global__ __launch_bounds__(256) void mlp2_kernel(
        const float* __restrict__ y1,
        const unsigned short* __restrict__ W16,    // [256][128] bf16
        const float* __restrict__ b,
        float* __restrict__ y2, int G) {
    __shared__ unsigned short sW[256 * 128];
    __shared__ float sIn[16][256];
    int tid = threadIdx.x;
    for (int i = tid; i < 256 * 128 / 2; i += 256)
        reinterpret_cast<unsigned*>(sW)[i] = reinterpret_cast<const unsigned*>(W16)[i];
    int g0 = blockIdx.x * 16;
    for (int i = tid; i < 16 * 256; i += 256) {
        int g = i >> 8, k = i & 255;
        sIn[g][k] = (g0 + g < G) ? y1[(size_t)(g0 + g) * 256 + k] : 0.f;
    }
    __syncthreads();
    int o = tid & 127;
    int half = tid >> 7;
    float bias = b[o];
    for (int gg = 0; gg < 8; ++gg) {
        int g = half * 8 + gg;
        if (g0 + g >= G) break;
        float acc = bias;
        #pragma unroll 8
        for (int k = 0; k < 256; ++k)
            acc += sIn[g][k] * bf2f(sW[k * 128 + o]);
        y2[(size_t)(g0 + g) * 128 + o] = selu_f(acc);
    }
}

__global__ void mlp3_kernel(const float* __restrict__ y2, const float* __restrict__ W,
                            const float* __restrict__ b, float* __restrict__ out, int G) {
    int g = blockIdx.x * blockDim.x + threadIdx.x;
    if (g >= G) return;
    const float* in = y2 + (size_t)g * 128;
    float acc = b[0];
    #pragma unroll 8
    for (int k = 0; k < 128; ++k) acc += in[k] * W[k];
    out[g] = acc;
}

extern "C" void kernel_launch(void* const* d_in, const int* in_sizes, int n_in,
                              void* d_out, int out_size, void* d_ws, size_t ws_size,
                              hipStream_t stream) {
    const float* feats_node  = (const float*)d_in[0];
    const float* feats_graph = (const float*)d_in[1];
    const int*   src         = (const int*)d_in[2];
    const int*   dst         = (const int*)d_in[3];
    const int*   node2graph  = (const int*)d_in[4];
    const float* W1 = (const float*)d_in[5];
    const float* b1 = (const float*)d_in[6];
    const float* W2 = (const float*)d_in[7];
    const float* b2 = (const float*)d_in[8];
    const float* W3 = (const float*)d_in[9];
    const float* b3 = (const float*)d_in[10];
    const float* L1w = (const float*)d_in[11];
    const float* L1b = (const float*)d_in[12];
    const float* L2w = (const float*)d_in[13];
    const float* L2b = (const float*)d_in[14];
    const float* L3w = (const float*)d_in[15];
    const float* L3b = (const float*)d_in[16];

    const int N = in_sizes[0] / 64;
    const int G = in_sizes[1] / 3;
    const int E = in_sizes[2];
    const int NBKT = (N + 255) >> 8;
    const int nmat = NBKT * NBLK;
    const int nscan = 2 * nmat;                      // cntD|cntS concatenated
    const int NBsc = (nscan + SCAN_B - 1) / SCAN_B;

    // ---- workspace layout ----
    int* iws = (int*)d_ws;
    int* deg_out_i = iws;                      // N
    int* deg_in_i  = deg_out_i + N;            // N
    int* row_start = deg_in_i + N;             // N
    int* bsums     = row_start + N;            // NBsc (<=512)
    int* cntD      = bsums + 512;              // nmat  (cntS must follow contiguously)
    int* cntS      = cntD + nmat;              // nmat
    int* csr_src   = cntS + nmat;              // E

    float* norm_out = (float*)(csr_src + E);   // N

    unsigned short* feats16 = (unsigned short*)(norm_out + N);    // [N][64]
    unsigned short* x16     = feats16 + (size_t)N * 64;           // [N][128]
    unsigned short* agg16   = x16 + (size_t)N * 128;              // [N][128]
    unsigned short* y16     = agg16 + (size_t)N * 128;            // [N][128]
    unsigned short* Wt1     = y16 + (size_t)N * 128;              // 128*64
    unsigned short* Wt2     = Wt1 + 128 * 64;                     // 128*128
    unsigned short* Wt3     = Wt2 + 128 * 128;                    // 128*128
    unsigned short* L1w16   = Wt3 + 128 * 128;                    // 131*256
    unsigned short* L2w16   = L1w16 + 131 * 256;                  // 256*128

    float* y1   = (float*)(L2w16 + 256 * 128); // G*256
    float* y2   = y1 + (size_t)G * 256;        // G*128

    // pairs/sbuf alias y16 (dead until layer-3 GEMM output; preprocessing finishes first)
    uint2* pairs = (uint2*)(((uintptr_t)y16 + 15) & ~(uintptr_t)15);  // E uint2
    int*   sbuf  = (int*)(pairs + E);                                  // E ints
    int*   sbufm = sbuf - E;   // virtual base: cntS carries +E from concatenated scan

    float* out = (float*)d_out;

    // ---- 1. weight prep (1 dispatch) ----
    {
        const int total = 128 * 64 + 2 * 128 * 128 + 131 * 256 / 4 + 256 * 128 / 4;
        prep_weights_kernel<<<(total + 255) / 256, 256, 0, stream>>>(
            W1, W2, W3, L1w, L2w, Wt1, Wt2, Wt3, L1w16, L2w16);
    }

    // ---- 2. bucket partition: hist + concatenated scan + scatter (5 dispatches) ----
    coarse_hist_kernel<<<NBLK, 256, 0, stream>>>(src, dst, cntD, cntS, E, NBKT);
    scan_block_sums<<<NBsc, 256, 0, stream>>>(cntD, bsums, nscan);
    scan_bsums<<<1, 256, 0, stream>>>(bsums, NBsc);
    scan_apply<<<NBsc, 256, 0, stream>>>(cntD, bsums, cntD, nscan);
    scatter_kernel<<<NBLK, 256, 0, stream>>>(src, dst, cntD, cntS, pairs, sbufm, E, NBKT);

    // ---- 3. fused bucket build: deg_out + CSR (1 dispatch) ----
    bucket_build_kernel<<<NBKT, 256, 0, stream>>>(
        sbufm, pairs, cntD, cntS, deg_out_i, row_start, deg_in_i, csr_src, N, E, NBKT);

    // ---- 4. features -> bf16 prescaled (norm_out inline) (1 dispatch) ----
    cvt_feats_kernel<<<(8 * N + 255) / 256, 256, 0, stream>>>(
        feats_node, deg_out_i, norm_out, feats16, N);

    const int gemm_grid = (N + 127) / 128;

    // ---- 5. layer 1 (FIN=64) ----
    csr_agg_kernel<8, 64><<<(N + 31) / 32, 256, 0, stream>>>(
        feats16, row_start, deg_in_i, csr_src, agg16, N);
    gemm_mfma_kernel<64, true, true><<<gemm_grid, 256, 0, stream>>>(
        agg16, Wt1, b1, norm_out, x16, N);

    // ---- 6. layer 2 (FIN=128) ----
    csr_agg_kernel<16, 128><<<(N + 15) / 16, 256, 0, stream>>>(
        x16, row_start, deg_in_i, csr_src, agg16, N);
    gemm_mfma_kernel<128, true, true><<<gemm_grid, 256, 0, stream>>>(
        agg16, Wt2, b2, norm_out, x16, N);

    // ---- 7. layer 3 (FIN=128, no selu, unscaled out for readout) ----
    csr_agg_kernel<16, 128><<<(N + 15) / 16, 256, 0, stream>>>(
        x16, row_start, deg_in_i, csr_src, agg16, N);
    gemm_mfma_kernel<128, false, false><<<gemm_grid, 256, 0, stream>>>(
        agg16, Wt3, b3, norm_out, y16, N);

    // ---- 8. MLP head (readout fused into mlp1) ----
    mlp1_kernel<<<(G + 15) / 16, 256, 0, stream>>>(
        y16, node2graph, feats_graph, L1w16, L1b, y1, N, G);
    mlp2_kernel<<<(G + 15) / 16, 256, 0, stream>>>(y1, L2w16, L2b, y2, G);
    mlp3_kernel<<<(G + 255) / 256, 256, 0, stream>>>(y2, L3w, L3b, out, G);
}

// Round 14
// 420.908 us; speedup vs baseline: 1.5095x; 1.0895x over previous
//
#include <hip/hip_runtime.h>
#include <math.h>

#define SELU_ALPHA 1.6732632423543772f
#define SELU_SCALE 1.0507009873554805f

#define NBLK 512          // partition blocks (E divides exactly: 512*3125)
#define MAXBKT 512        // static LDS sizing; actual NBKT = ceil(N/256)

typedef __attribute__((ext_vector_type(8))) short bf16x8;
typedef __attribute__((ext_vector_type(4))) float f32x4;

__device__ __forceinline__ float selu_f(float x) {
    return SELU_SCALE * (x > 0.f ? x : SELU_ALPHA * expm1f(x));
}

__device__ __forceinline__ float bf2f(unsigned short u) {
    return __uint_as_float(((unsigned)u) << 16);
}
__device__ __forceinline__ unsigned short f2bf(float f) {
    unsigned u = __float_as_uint(f);
    unsigned r = (u + 0x7fffu + ((u >> 16) & 1u)) >> 16;
    return (unsigned short)r;
}

// ---- scan stage 1: per-block sums (over concatenated cntD|cntS) ----
#define SCAN_B 1024

__global__ __launch_bounds__(256) void scan_block_sums(const int* __restrict__ in,
                                                       int* __restrict__ bsums, int n) {
    __shared__ int s[256];
    int b = blockIdx.x, t = threadIdx.x;
    int base = b * SCAN_B;
    int sum = 0;
    for (int i = t; i < SCAN_B; i += 256) {
        int idx = base + i;
        sum += (idx < n) ? in[idx] : 0;
    }
    s[t] = sum; __syncthreads();
    for (int off = 128; off > 0; off >>= 1) {
        if (t < off) s[t] += s[t + off];
        __syncthreads();
    }
    if (t == 0) bsums[b] = s[0];
}

// ---- scan stage 2 (fused): each block scans bsums (<=512) in LDS for its own
//      exclusive offset, then applies the in-block scan. In-place safe. ----
__global__ __launch_bounds__(256) void scan_apply2(const int* __restrict__ in,
                                                   const int* __restrict__ bsums,
                                                   int* __restrict__ out, int n, int nb) {
    __shared__ int sb[512];
    __shared__ int s[256];
    __shared__ int blockoff;
    int b = blockIdx.x, t = threadIdx.x;

    // scan the block sums (nb <= 512) with 2 elems/thread, doubling scan
    int orig0 = (t < nb) ? bsums[t] : 0;
    int orig1 = (t + 256 < nb) ? bsums[t + 256] : 0;
    sb[t] = orig0; sb[t + 256] = orig1;
    __syncthreads();
    for (int off = 1; off < 512; off <<= 1) {
        int v0 = (t >= off) ? sb[t - off] : 0;
        int v1 = (t + 256 >= off) ? sb[t + 256 - off] : 0;
        __syncthreads();
        sb[t] += v0; sb[t + 256] += v1;
        __syncthreads();
    }
    if (t == (b & 255)) {
        bool hi = b >= 256;
        int incl = hi ? sb[t + 256] : sb[t];
        int orig = hi ? orig1 : orig0;
        blockoff = incl - orig;   // exclusive prefix of block b
    }
    __syncthreads();

    // in-block scan + apply (4 elems/thread)
    int idx0 = b * SCAN_B + t * 4;
    int v[4]; int tsum = 0;
    #pragma unroll
    for (int k = 0; k < 4; ++k) {
        int idx = idx0 + k;
        v[k] = (idx < n) ? in[idx] : 0;
        tsum += v[k];
    }
    s[t] = tsum; __syncthreads();
    for (int off = 1; off < 256; off <<= 1) {
        int x = (t >= off) ? s[t - off] : 0;
        __syncthreads();
        s[t] += x;
        __syncthreads();
    }
    int run = s[t] - tsum + blockoff;
    #pragma unroll
    for (int k = 0; k < 4; ++k) {
        int idx = idx0 + k;
        if (idx < n) out[idx] = run;
        run += v[k];
    }
}

// ---- K1: per-block coarse histograms of dst>>8 and src>>8 (LDS atomics only) ----
__global__ __launch_bounds__(256) void coarse_hist_kernel(
        const int* __restrict__ src, const int* __restrict__ dst,
        int* __restrict__ cntD, int* __restrict__ cntS, int E, int nbkt) {
    __shared__ int hD[MAXBKT];
    __shared__ int hS[MAXBKT];
    int bb = blockIdx.x, t = threadIdx.x;
    for (int k = t; k < MAXBKT; k += 256) { hD[k] = 0; hS[k] = 0; }
    __syncthreads();
    int chunk = E / NBLK;                 // exact
    int beg = bb * chunk, end = beg + chunk;
    for (int i = beg + t; i < end; i += 256) {
        atomicAdd(&hD[((unsigned)dst[i]) >> 8], 1);
        atomicAdd(&hS[((unsigned)src[i]) >> 8], 1);
    }
    __syncthreads();
    for (int k = t; k < nbkt; k += 256) {
        cntD[k * NBLK + bb] = hD[k];
        cntS[k * NBLK + bb] = hS[k];
    }
}

// ---- K2: scatter. cntS entries carry +E offset (concatenated scan); caller passes
//      sbufm = sbuf - E so writes land correctly. ----
__global__ __launch_bounds__(256) void scatter_kernel(
        const int* __restrict__ src, const int* __restrict__ dst,
        const int* __restrict__ cntD, const int* __restrict__ cntS,
        uint2* __restrict__ pairs, int* __restrict__ sbufm, int E, int nbkt) {
    __shared__ int cD[MAXBKT];
    __shared__ int cS[MAXBKT];
    int bb = blockIdx.x, t = threadIdx.x;
    for (int k = t; k < nbkt; k += 256) {
        cD[k] = cntD[k * NBLK + bb];
        cS[k] = cntS[k * NBLK + bb];
    }
    __syncthreads();
    int chunk = E / NBLK;
    int beg = bb * chunk, end = beg + chunk;
    for (int i = beg + t; i < end; i += 256) {
        unsigned s = (unsigned)src[i], d = (unsigned)dst[i];
        int pD = atomicAdd(&cD[d >> 8], 1);
        pairs[pD] = make_uint2(s, d);
        int pS = atomicAdd(&cS[s >> 8], 1);
        sbufm[pS] = (int)s;
    }
}

// ---- K3: fused bucket build: deg_out histogram + CSR (row_start, deg_in, csr_src) ----
__global__ __launch_bounds__(256) void bucket_build_kernel(
        const int* __restrict__ sbufm, const uint2* __restrict__ pairs,
        const int* __restrict__ cntD, const int* __restrict__ cntS,
        int* __restrict__ deg_out, int* __restrict__ row_start,
        int* __restrict__ deg_in, int* __restrict__ csr_src,
        int N, int E, int nbkt) {
    __shared__ int hist[256];
    __shared__ int sc[256];
    __shared__ int cur[256];
    int b = blockIdx.x, t = threadIdx.x;
    int node = (b << 8) + t;

    // part 1: deg_out from src-bucket values (indices carry +E offset)
    {
        int base = cntS[b * NBLK];
        int end = (b + 1 < nbkt) ? cntS[(b + 1) * NBLK] : 2 * E;
        hist[t] = 0; __syncthreads();
        for (int i = base + t; i < end; i += 256)
            atomicAdd(&hist[sbufm[i] & 255], 1);
        __syncthreads();
        if (node < N) deg_out[node] = hist[t];
        __syncthreads();
    }

    // part 2: CSR build from dst-bucket pairs
    {
        int base = cntD[b * NBLK];
        int end = (b + 1 < nbkt) ? cntD[(b + 1) * NBLK] : E;
        hist[t] = 0; __syncthreads();
        for (int i = base + t; i < end; i += 256)
            atomicAdd(&hist[pairs[i].y & 255], 1);
        __syncthreads();
        int v = hist[t];
        sc[t] = v; __syncthreads();
        for (int off = 1; off < 256; off <<= 1) {
            int x = (t >= off) ? sc[t - off] : 0;
            __syncthreads();
            sc[t] += x;
            __syncthreads();
        }
        int ex = sc[t] - v;
        cur[t] = base + ex;
        if (node < N) { row_start[node] = base + ex; deg_in[node] = v; }
        __syncthreads();
        for (int i = base + t; i < end; i += 256) {
            uint2 p = pairs[i];
            int pos = atomicAdd(&cur[p.y & 255], 1);
            csr_src[pos] = (int)p.x;
        }
    }
}

// ---- prep: all weight conversions in ONE dispatch ----
__global__ void prep_weights_kernel(
        const float* __restrict__ W1, const float* __restrict__ W2,
        const float* __restrict__ W3, const float* __restrict__ L1w,
        const float* __restrict__ L2w,
        unsigned short* __restrict__ Wt1, unsigned short* __restrict__ Wt2,
        unsigned short* __restrict__ Wt3, unsigned short* __restrict__ L1w16,
        unsigned short* __restrict__ L2w16) {
    const int s0 = 128 * 64, s1 = 128 * 128, s2 = 128 * 128;
    const int s3 = 131 * 256 / 4, s4 = 256 * 128 / 4;
    int i = blockIdx.x * 256 + threadIdx.x;
    if (i < s0) {
        int col = i / 64, k = i % 64;
        Wt1[i] = f2bf(W1[k * 128 + col]);
        return;
    }
    i -= s0;
    if (i < s1) {
        int col = i / 128, k = i % 128;
        Wt2[i] = f2bf(W2[k * 128 + col]);
        return;
    }
    i -= s1;
    if (i < s2) {
        int col = i / 128, k = i % 128;
        Wt3[i] = f2bf(W3[k * 128 + col]);
        return;
    }
    i -= s2;
    if (i < s3) {
        float4 v = reinterpret_cast<const float4*>(L1w)[i];
        unsigned short o[4] = { f2bf(v.x), f2bf(v.y), f2bf(v.z), f2bf(v.w) };
        reinterpret_cast<uint2*>(L1w16)[i] = *reinterpret_cast<uint2*>(o);
        return;
    }
    i -= s3;
    if (i < s4) {
        float4 v = reinterpret_cast<const float4*>(L2w)[i];
        unsigned short o[4] = { f2bf(v.x), f2bf(v.y), f2bf(v.z), f2bf(v.w) };
        reinterpret_cast<uint2*>(L2w16)[i] = *reinterpret_cast<uint2*>(o);
    }
}

// ---- prep: feats -> bf16 prescaled by norm_out (computed inline); stores norm_out ----
__global__ void cvt_feats_kernel(const float* __restrict__ feats,
                                 const int* __restrict__ deg_out,
                                 float* __restrict__ norm_out,
                                 unsigned short* __restrict__ outp, int N) {
    int i = blockIdx.x * blockDim.x + threadIdx.x;   // i = n*8 + chunk
    if (i >= 8 * N) return;
    int n = i >> 3, c = i & 7;
    float no = 1.f / sqrtf(fmaxf((float)deg_out[n], 1.f));
    if (c == 0) norm_out[n] = no;
    const float* fp = feats + (size_t)n * 64 + c * 8;
    float4 a = *reinterpret_cast<const float4*>(fp);
    float4 b = *reinterpret_cast<const float4*>(fp + 4);
    unsigned short o[8] = { f2bf(a.x * no), f2bf(a.y * no), f2bf(a.z * no), f2bf(a.w * no),
                            f2bf(b.x * no), f2bf(b.y * no), f2bf(b.z * no), f2bf(b.w * no) };
    *reinterpret_cast<float4*>(outp + (size_t)n * 64 + c * 8) = *reinterpret_cast<float4*>(o);
}

// ---- gather-aggregate with shuffle-broadcast + next-chunk index prefetch ----
// agg16[n] = f2bf(nin(n) * sum_e x16[csr_src[e]])   (x16 prescaled by norm_out)
template<int TPG, int FIN>   // TPG = FIN/8
__global__ __launch_bounds__(256) void csr_agg_kernel(
        const unsigned short* __restrict__ x, const int* __restrict__ row_start,
        const int* __restrict__ deg_in, const int* __restrict__ csr_src,
        unsigned short* __restrict__ agg, int N) {
    const int GPB = 256 / TPG;
    int g = threadIdx.x / TPG;
    int j = threadIdx.x % TPG;
    int n = blockIdx.x * GPB + g;
    if (n >= N) return;
    const int lane = threadIdx.x & 63;
    const int gbase = lane & ~(TPG - 1);   // group base lane within wave
    int beg = row_start[n];
    int dg = deg_in[n];
    int end = beg + dg;
    float nin = 1.f / sqrtf(fmaxf((float)dg, 1.f));
    float acc[8] = {0.f, 0.f, 0.f, 0.f, 0.f, 0.f, 0.f, 0.f};
    int myIdx = (beg + j < end) ? csr_src[beg + j] : 0;
    for (int c = beg; c < end; c += TPG) {
        int cnt = end - c;                 // uniform within group
        int nxtIdx = (c + TPG + j < end) ? csr_src[c + TPG + j] : 0;  // prefetch
        float4 v[TPG];
        #pragma unroll
        for (int t = 0; t < TPG; ++t) {
            if (t < cnt) {
                int s = __shfl(myIdx, gbase + t, 64);
                v[t] = *reinterpret_cast<const float4*>(&x[(size_t)s * FIN + j * 8]);
            }
        }
        #pragma unroll
        for (int t = 0; t < TPG; ++t) {
            if (t < cnt) {
                const unsigned short* u = reinterpret_cast<const unsigned short*>(&v[t]);
                #pragma unroll
                for (int k = 0; k < 8; ++k) acc[k] += bf2f(u[k]);
            }
        }
        myIdx = nxtIdx;
    }
    unsigned short ov[8];
    #pragma unroll
    for (int k = 0; k < 8; ++k) ov[k] = f2bf(acc[k] * nin);
    *reinterpret_cast<float4*>(&agg[(size_t)n * FIN + j * 8]) = *reinterpret_cast<float4*>(ov);
}

// ---- MFMA node GEMM: W in LDS only (34.8KB -> 4 blocks/CU), A streamed from global ----
template<int FIN, bool SELU, bool SCALE_OUT>
__global__ __launch_bounds__(256, 4) void gemm_mfma_kernel(
        const unsigned short* __restrict__ agg16,  // [N][FIN] bf16
        const unsigned short* __restrict__ Wt,     // [128][FIN] bf16
        const float* __restrict__ b,
        const float* __restrict__ norm_out,
        unsigned short* __restrict__ out,          // [N][128] bf16
        int N) {
    const int PAD = 8;
    const int LDW = FIN + PAD;
    const int CH = FIN / 8;
    __shared__ unsigned short sW[128 * LDW];
    const int tid = threadIdx.x;
    const int wave = tid >> 6, lane = tid & 63;
    const int wr = (wave >> 1) * 64;
    const int wc = (wave & 1) * 64;
    const int n0 = blockIdx.x * 128;

    for (int i = tid; i < 128 * CH; i += 256) {
        int col = i / CH, kc = i % CH;
        *reinterpret_cast<float4*>(&sW[col * LDW + kc * 8]) =
            *reinterpret_cast<const float4*>(&Wt[col * FIN + kc * 8]);
    }
    __syncthreads();

    const int l16 = lane & 15;
    const int lk = (lane >> 4) * 8;
    const bf16x8 zero8 = (bf16x8){0,0,0,0,0,0,0,0};
    f32x4 acc[4][4];
    #pragma unroll
    for (int mi = 0; mi < 4; ++mi)
        #pragma unroll
        for (int ci = 0; ci < 4; ++ci)
            acc[mi][ci] = (f32x4){0.f, 0.f, 0.f, 0.f};

    #pragma unroll
    for (int k0 = 0; k0 < FIN; k0 += 32) {
        bf16x8 a[4], w[4];
        #pragma unroll
        for (int mi = 0; mi < 4; ++mi) {
            int n = n0 + wr + mi * 16 + l16;
            a[mi] = (n < N)
                ? *reinterpret_cast<const bf16x8*>(&agg16[(size_t)n * FIN + k0 + lk])
                : zero8;
        }
        #pragma unroll
        for (int ci = 0; ci < 4; ++ci)
            w[ci] = *reinterpret_cast<const bf16x8*>(&sW[(wc + ci * 16 + l16) * LDW + k0 + lk]);
        #pragma unroll
        for (int mi = 0; mi < 4; ++mi)
            #pragma unroll
            for (int ci = 0; ci < 4; ++ci)
                acc[mi][ci] = __builtin_amdgcn_mfma_f32_16x16x32_bf16(
                    a[mi], w[ci], acc[mi][ci], 0, 0, 0);
    }

    // D frag: col = lane&15, row = (lane>>4)*4 + r
    const int rbase = (lane >> 4) * 4;
    #pragma unroll
    for (int ci = 0; ci < 4; ++ci) {
        int col = wc + ci * 16 + l16;
        float bias = b[col];
        #pragma unroll
        for (int mi = 0; mi < 4; ++mi) {
            #pragma unroll
            for (int r = 0; r < 4; ++r) {
                int n = n0 + wr + mi * 16 + rbase + r;
                if (n < N) {
                    float v = acc[mi][ci][r] + bias;
                    if (SELU) v = selu_f(v);
                    if (SCALE_OUT) v *= norm_out[n];
                    out[(size_t)n * 128 + col] = f2bf(v);
                }
            }
        }
    }
}

// ---- MLP layer 1 with FUSED readout: per block, 16 graphs ----
__global__ __launch_bounds__(256) void mlp1_kernel(
        const unsigned short* __restrict__ y16,    // [N][128] bf16
        const int* __restrict__ n2g,               // [N] sorted
        const float* __restrict__ fg,              // [G][3]
        const unsigned short* __restrict__ W16,    // [131][256] bf16
        const float* __restrict__ b,
        float* __restrict__ y1, int N, int G) {
    __shared__ unsigned short sW[131 * 256];
    __shared__ float sIn[16][132];
    int tid = threadIdx.x;
    for (int i = tid; i < 131 * 256 / 2; i += 256)
        reinterpret_cast<unsigned*>(sW)[i] = reinterpret_cast<const unsigned*>(W16)[i];

    int grp = tid >> 4;         // graph within block
    int l16 = tid & 15;         // 8-col slice
    int g = blockIdx.x * 16 + grp;
    float a8[8] = {0.f, 0.f, 0.f, 0.f, 0.f, 0.f, 0.f, 0.f};
    if (g < G) {
        int beg, end;
        {
            int lo = 0, hi = N;
            while (lo < hi) { int m = (lo + hi) >> 1; if (n2g[m] < g) lo = m + 1; else hi = m; }
            beg = lo;
            lo = beg; hi = N;
            while (lo < hi) { int m = (lo + hi) >> 1; if (n2g[m] < g + 1) lo = m + 1; else hi = m; }
            end = lo;
        }
        for (int n = beg; n < end; ++n) {
            float4 raw = *reinterpret_cast<const float4*>(&y16[(size_t)n * 128 + l16 * 8]);
            const unsigned short* u = reinterpret_cast<const unsigned short*>(&raw);
            #pragma unroll
            for (int k = 0; k < 8; ++k) a8[k] += bf2f(u[k]);
        }
    }
    #pragma unroll
    for (int k = 0; k < 8; ++k) sIn[grp][l16 * 8 + k] = a8[k];
    if (l16 == 0) {
        if (g < G) {
            sIn[grp][128] = fg[(size_t)g * 3 + 0];
            sIn[grp][129] = fg[(size_t)g * 3 + 1];
            sIn[grp][130] = fg[(size_t)g * 3 + 2];
        } else {
            sIn[grp][128] = 0.f; sIn[grp][129] = 0.f; sIn[grp][130] = 0.f;
        }
    }
    __syncthreads();

    int g0 = blockIdx.x * 16;
    float bias = b[tid];
    for (int gg = 0; gg < 16; ++gg) {
        if (g0 + gg >= G) break;
        float acc = bias;
        #pragma unroll 8
        for (int k = 0; k < 131; ++k)
            acc += sIn[gg][k] * bf2f(sW[k * 256 + tid]);
        y1[(size_t)(g0 + gg) * 256 + tid] = selu_f(acc);
    }
}

// ---- MLP layers 2+3 fused: y2 stays in registers; wave-reduce dot with L3w ----
__global__ __launch_bounds__(256) void mlp23_kernel(
        const float* __restrict__ y1,
        const unsigned short* __restrict__ W16,    // [256][128] bf16
        const float* __restrict__ b2v,
        const float* __restrict__ L3w,             // [128]
        const float* __restrict__ L3b,             // [1]
        float* __restrict__ out, int G) {
    __shared__ unsigned short sW[256 * 128];
    __shared__ float sIn[16][256];
    __shared__ float sL3[128];
    __shared__ float red[16][2];
    int tid = threadIdx.x;
    for (int i = tid; i < 256 * 128 / 2; i += 256)
        reinterpret_cast<unsigned*>(sW)[i] = reinterpret_cast<const unsigned*>(W16)[i];
    if (tid < 128) sL3[tid] = L3w[tid];
    int g0 = blockIdx.x * 16;
    for (int i = tid; i < 16 * 256; i += 256) {
        int g = i >> 8, k = i & 255;
        sIn[g][k] = (g0 + g < G) ? y1[(size_t)(g0 + g) * 256 + k] : 0.f;
    }
    __syncthreads();
    int o = tid & 127;
    int half = tid >> 7;
    int lane = tid & 63;
    int wv = tid >> 6;             // 0..3; waves (2*half, 2*half+1) share graphs
    float bias = b2v[o];
    float w3 = sL3[o];
    for (int gg = 0; gg < 8; ++gg) {
        int g = half * 8 + gg;
        float acc = bias;
        #pragma unroll 8
        for (int k = 0; k < 256; ++k)
            acc += sIn[g][k] * bf2f(sW[k * 128 + o]);
        float v = selu_f(acc) * w3;
        #pragma unroll
        for (int off = 32; off > 0; off >>= 1)
            v += __shfl_down(v, off, 64);
        if (lane == 0) red[g][wv & 1] = v;
    }
    __syncthreads();
    if (tid < 16) {
        int g = g0 + tid;
        if (g < G) out[g] = red[tid][0] + red[tid][1] + L3b[0];
    }
}

extern "C" void kernel_launch(void* const* d_in, const int* in_sizes, int n_in,
                              void* d_out, int out_size, void* d_ws, size_t ws_size,
                              hipStream_t stream) {
    const float* feats_node  = (const float*)d_in[0];
    const float* feats_graph = (const float*)d_in[1];
    const int*   src         = (const int*)d_in[2];
    const int*   dst         = (const int*)d_in[3];
    const int*   node2graph  = (const int*)d_in[4];
    const float* W1 = (const float*)d_in[5];
    const float* b1 = (const float*)d_in[6];
    const float* W2 = (const float*)d_in[7];
    const float* b2 = (const float*)d_in[8];
    const float* W3 = (const float*)d_in[9];
    const float* b3 = (const float*)d_in[10];
    const float* L1w = (const float*)d_in[11];
    const float* L1b = (const float*)d_in[12];
    const float* L2w = (const float*)d_in[13];
    const float* L2b = (const float*)d_in[14];
    const float* L3w = (const float*)d_in[15];
    const float* L3b = (const float*)d_in[16];

    const int N = in_sizes[0] / 64;
    const int G = in_sizes[1] / 3;
    const int E = in_sizes[2];
    const int NBKT = (N + 255) >> 8;
    const int nmat = NBKT * NBLK;
    const int nscan = 2 * nmat;                      // cntD|cntS concatenated
    const int NBsc = (nscan + SCAN_B - 1) / SCAN_B;  // <=512 required by scan_apply2

    // ---- workspace layout ----
    int* iws = (int*)d_ws;
    int* deg_out_i = iws;                      // N
    int* deg_in_i  = deg_out_i + N;            // N
    int* row_start = deg_in_i + N;             // N
    int* bsums     = row_start + N;            // NBsc (<=512)
    int* cntD      = bsums + 512;              // nmat  (cntS must follow contiguously)
    int* cntS      = cntD + nmat;              // nmat
    int* csr_src   = cntS + nmat;              // E

    float* norm_out = (float*)(csr_src + E);   // N

    unsigned short* feats16 = (unsigned short*)(norm_out + N);    // [N][64]
    unsigned short* x16     = feats16 + (size_t)N * 64;           // [N][128]
    unsigned short* agg16   = x16 + (size_t)N * 128;              // [N][128]
    unsigned short* y16     = agg16 + (size_t)N * 128;            // [N][128]
    unsigned short* Wt1     = y16 + (size_t)N * 128;              // 128*64
    unsigned short* Wt2     = Wt1 + 128 * 64;                     // 128*128
    unsigned short* Wt3     = Wt2 + 128 * 128;                    // 128*128
    unsigned short* L1w16   = Wt3 + 128 * 128;                    // 131*256
    unsigned short* L2w16   = L1w16 + 131 * 256;                  // 256*128

    float* y1   = (float*)(L2w16 + 256 * 128); // G*256

    // pairs/sbuf alias y16 (dead until layer-3 GEMM output; preprocessing finishes first)
    uint2* pairs = (uint2*)(((uintptr_t)y16 + 15) & ~(uintptr_t)15);  // E uint2
    int*   sbuf  = (int*)(pairs + E);                                  // E ints
    int*   sbufm = sbuf - E;   // virtual base: cntS carries +E from concatenated scan

    float* out = (float*)d_out;

    // ---- 1. weight prep (1 dispatch) ----
    {
        const int total = 128 * 64 + 2 * 128 * 128 + 131 * 256 / 4 + 256 * 128 / 4;
        prep_weights_kernel<<<(total + 255) / 256, 256, 0, stream>>>(
            W1, W2, W3, L1w, L2w, Wt1, Wt2, Wt3, L1w16, L2w16);
    }

    // ---- 2. bucket partition: hist + 2-stage scan + scatter (4 dispatches) ----
    coarse_hist_kernel<<<NBLK, 256, 0, stream>>>(src, dst, cntD, cntS, E, NBKT);
    scan_block_sums<<<NBsc, 256, 0, stream>>>(cntD, bsums, nscan);
    scan_apply2<<<NBsc, 256, 0, stream>>>(cntD, bsums, cntD, nscan, NBsc);
    scatter_kernel<<<NBLK, 256, 0, stream>>>(src, dst, cntD, cntS, pairs, sbufm, E, NBKT);

    // ---- 3. fused bucket build: deg_out + CSR (1 dispatch) ----
    bucket_build_kernel<<<NBKT, 256, 0, stream>>>(
        sbufm, pairs, cntD, cntS, deg_out_i, row_start, deg_in_i, csr_src, N, E, NBKT);

    // ---- 4. features -> bf16 prescaled (norm_out inline) (1 dispatch) ----
    cvt_feats_kernel<<<(8 * N + 255) / 256, 256, 0, stream>>>(
        feats_node, deg_out_i, norm_out, feats16, N);

    const int gemm_grid = (N + 127) / 128;

    // ---- 5. layer 1 (FIN=64) ----
    csr_agg_kernel<8, 64><<<(N + 31) / 32, 256, 0, stream>>>(
        feats16, row_start, deg_in_i, csr_src, agg16, N);
    gemm_mfma_kernel<64, true, true><<<gemm_grid, 256, 0, stream>>>(
        agg16, Wt1, b1, norm_out, x16, N);

    // ---- 6. layer 2 (FIN=128) ----
    csr_agg_kernel<16, 128><<<(N + 15) / 16, 256, 0, stream>>>(
        x16, row_start, deg_in_i, csr_src, agg16, N);
    gemm_mfma_kernel<128, true, true><<<gemm_grid, 256, 0, stream>>>(
        agg16, Wt2, b2, norm_out, x16, N);

    // ---- 7. layer 3 (FIN=128, no selu, unscaled out for readout) ----
    csr_agg_kernel<16, 128><<<(N + 15) / 16, 256, 0, stream>>>(
        x16, row_start, deg_in_i, csr_src, agg16, N);
    gemm_mfma_kernel<128, false, false><<<gemm_grid, 256, 0, stream>>>(
        agg16, Wt3, b3, norm_out, y16, N);

    // ---- 8. MLP head (readout fused into mlp1; mlp2+mlp3 fused) ----
    mlp1_kernel<<<(G + 15) / 16, 256, 0, stream>>>(
        y16, node2graph, feats_graph, L1w16, L1b, y1, N, G);
    mlp23_kernel<<<(G + 15) / 16, 256, 0, stream>>>(
        y1, L2w16, L2b, L3w, L3b, out, G);
}